// Round 6
// baseline (1990.611 us; speedup 1.0000x reference)
//
#include <hip/hip_runtime.h>
#include <math.h>

// ---- problem constants ----
#define D_MODELC 2048
#define D_INNERC 4096
#define NH 64        // H heads
#define DHEAD 64     // D_HEAD
#define NST 128      // N state dim
#define NG 8         // G groups
#define CHUNKC 256
#define GNC 1024     // G*N
#define CONV_DIMC 6144
#define IN_PROJC 10304
#define BATCH 2
#define SEQ 2048
#define NCHUNK 8
#define ROWS 4096
// proj column map: [X 0:4096 | A_dt 4096:4160 | B 4160:5184 | C 5184:6208 | gate 6208:10304]

typedef __attribute__((ext_vector_type(8))) short bf16x8;
typedef __attribute__((ext_vector_type(4))) float f32x4;

__device__ __forceinline__ float bf2f(unsigned short h) {
  return __uint_as_float(((unsigned)h) << 16);
}
__device__ __forceinline__ unsigned short f2bf(float f) {
  unsigned u = __float_as_uint(f);
  u += 0x7FFFu + ((u >> 16) & 1u);   // round-to-nearest-even
  return (unsigned short)(u >> 16);
}
// HW packed conversion: dst.lo16 = bf16(a), dst.hi16 = bf16(b)
__device__ __forceinline__ unsigned cvtpk(float a, float b) {
  unsigned r;
  asm("v_cvt_pk_bf16_f32 %0, %1, %2" : "=v"(r) : "v"(a), "v"(b));
  return r;
}
__device__ __forceinline__ uint4 pack8_cvt(const float* f) {
  uint4 r;
  r.x = cvtpk(f[0], f[1]); r.y = cvtpk(f[2], f[3]);
  r.z = cvtpk(f[4], f[5]); r.w = cvtpk(f[6], f[7]);
  return r;
}
// residual f - bf2f(packed hi)
__device__ __forceinline__ void resid8(const float* f, uint4 q, float* lo) {
  lo[0] = f[0] - __uint_as_float(q.x << 16);
  lo[1] = f[1] - __uint_as_float(q.x & 0xffff0000u);
  lo[2] = f[2] - __uint_as_float(q.y << 16);
  lo[3] = f[3] - __uint_as_float(q.y & 0xffff0000u);
  lo[4] = f[4] - __uint_as_float(q.z << 16);
  lo[5] = f[5] - __uint_as_float(q.z & 0xffff0000u);
  lo[6] = f[6] - __uint_as_float(q.w << 16);
  lo[7] = f[7] - __uint_as_float(q.w & 0xffff0000u);
}
__device__ __forceinline__ float siluf(float x) { return x / (1.0f + expf(-x)); }

__device__ __forceinline__ float block_sum256(float v) {
#pragma unroll
  for (int off = 32; off > 0; off >>= 1) v += __shfl_down(v, off, 64);
  __shared__ float red[4];
  const int lane = threadIdx.x & 63, wv = threadIdx.x >> 6;
  if (lane == 0) red[wv] = v;
  __syncthreads();
  float s = red[0] + red[1] + red[2] + red[3];
  __syncthreads();
  return s;
}

// ---------------- 1. input rmsnorm -> bf16 hi/lo planes ----------------
__global__ __launch_bounds__(256) void rmsnorm_in_kernel(
    const float* __restrict__ x, const float* __restrict__ nw,
    unsigned short* __restrict__ xnhi, unsigned short* __restrict__ xnlo) {
  const int row = blockIdx.x;
  const int tid = threadIdx.x;
  const float4* xr = (const float4*)(x + (size_t)row * D_MODELC);
  float4 v[2];
  float ss = 0.f;
#pragma unroll
  for (int i = 0; i < 2; ++i) {
    v[i] = xr[tid + i * 256];
    ss += v[i].x * v[i].x + v[i].y * v[i].y + v[i].z * v[i].z + v[i].w * v[i].w;
  }
  ss = block_sum256(ss);
  const float rms = rsqrtf(ss * (1.0f / D_MODELC) + 1e-6f);
  const float4* wp = (const float4*)nw;
#pragma unroll
  for (int i = 0; i < 2; ++i) {
    const int idx = tid + i * 256;
    const float4 w4 = wp[idx];
    float a = v[i].x * rms * w4.x;
    float b = v[i].y * rms * w4.y;
    float c = v[i].z * rms * w4.z;
    float d = v[i].w * rms * w4.w;
    unsigned h0 = cvtpk(a, b), h1 = cvtpk(c, d);
    float la = a - __uint_as_float(h0 << 16);
    float lb = b - __uint_as_float(h0 & 0xffff0000u);
    float lc = c - __uint_as_float(h1 << 16);
    float ld = d - __uint_as_float(h1 & 0xffff0000u);
    unsigned l0 = cvtpk(la, lb), l1 = cvtpk(lc, ld);
    *(uint2*)&xnhi[(size_t)row * D_MODELC + idx * 4] = make_uint2(h0, h1);
    *(uint2*)&xnlo[(size_t)row * D_MODELC + idx * 4] = make_uint2(l0, l1);
  }
}

// ---------------- 2. MFMA GEMM: C[M,N] = A[M,K] @ W[N,K]^T ----------------
// AMODE 1: A = single bf16 plane (Ahi). AMODE 2: A = bf16 hi+lo planes.
// SPLITW: W split hi/lo, 3-MFMA accumulation (demoted to 1-MFMA for gate-only
//         blocks n0>=6272 at runtime -- gate only feeds `out`).
// EPI==0: route proj columns to convin/A_dt/gate. EPI==1: Cout = acc + res.
template <int AMODE, bool SPLITW, int EPI>
__global__ __launch_bounds__(256) void mfma_gemm(
    const unsigned short* __restrict__ Ahi, const unsigned short* __restrict__ Alo, int lda,
    const float* __restrict__ W, int N, int K,
    unsigned short* __restrict__ convin, float* __restrict__ A_dt,
    unsigned short* __restrict__ gate,
    float* __restrict__ Cout, const float* __restrict__ res, int ldc) {
  __shared__ unsigned short As_hi[128 * 32];
  __shared__ unsigned short Bs_hi[128 * 32];
  __shared__ unsigned short As_lo[128 * 32];
  __shared__ unsigned short Bs_lo[128 * 32];

  const int tid = threadIdx.x;
  const int m0 = blockIdx.x * 128;
  const int n0 = blockIdx.y * 128;
  const int lane = tid & 63, wv = tid >> 6;
  const int wr = (wv >> 1) * 64, wc = (wv & 1) * 64;
  const int fr = lane & 15, kb = lane >> 4;
  const int srow = tid >> 1;     // staging row 0..127
  const int shalf = tid & 1;     // k half (16 each)

  const bool do_split = SPLITW && (n0 < 6272);  // gate-only blocks: plain bf16

  f32x4 acc[4][4];
#pragma unroll
  for (int i = 0; i < 4; ++i)
#pragma unroll
    for (int j = 0; j < 4; ++j) acc[i][j] = (f32x4){0.f, 0.f, 0.f, 0.f};

  const int c0s = (shalf * 2) ^ (srow & 3);       // swizzled 16B-chunk ids
  const int c1s = (shalf * 2 + 1) ^ (srow & 3);
  const int wbase = srow * 32;

  for (int k0 = 0; k0 < K; k0 += 32) {
    __syncthreads();
    // ---- stage A tile [128][32] (bf16 planes, no conversion) ----
    {
      const unsigned short* sh = Ahi + (size_t)(m0 + srow) * lda + k0 + shalf * 16;
      uint4 q0 = *(const uint4*)(sh);
      uint4 q1 = *(const uint4*)(sh + 8);
      *(uint4*)&As_hi[wbase + c0s * 8] = q0;
      *(uint4*)&As_hi[wbase + c1s * 8] = q1;
      if (AMODE == 2) {
        const unsigned short* sl = Alo + (size_t)(m0 + srow) * lda + k0 + shalf * 16;
        uint4 p0 = *(const uint4*)(sl);
        uint4 p1 = *(const uint4*)(sl + 8);
        *(uint4*)&As_lo[wbase + c0s * 8] = p0;
        *(uint4*)&As_lo[wbase + c1s * 8] = p1;
      }
    }
    // ---- stage W tile [128][32] (fp32 -> cvt_pk bf16) ----
    {
      const int gn = n0 + srow;
      float v[16];
      if (EPI == 0 && gn >= N) {
#pragma unroll
        for (int j = 0; j < 16; ++j) v[j] = 0.f;
      } else {
        const float* src = W + (size_t)gn * K + k0 + shalf * 16;
        *(float4*)&v[0] = *(const float4*)(src);
        *(float4*)&v[4] = *(const float4*)(src + 4);
        *(float4*)&v[8] = *(const float4*)(src + 8);
        *(float4*)&v[12] = *(const float4*)(src + 12);
      }
      uint4 qh0 = pack8_cvt(&v[0]);
      uint4 qh1 = pack8_cvt(&v[8]);
      *(uint4*)&Bs_hi[wbase + c0s * 8] = qh0;
      *(uint4*)&Bs_hi[wbase + c1s * 8] = qh1;
      if (do_split) {
        float lo[16];
        resid8(&v[0], qh0, &lo[0]);
        resid8(&v[8], qh1, &lo[8]);
        *(uint4*)&Bs_lo[wbase + c0s * 8] = pack8_cvt(&lo[0]);
        *(uint4*)&Bs_lo[wbase + c1s * 8] = pack8_cvt(&lo[8]);
      }
    }
    __syncthreads();

    // ---- fragments + MFMA ----
    bf16x8 ah[4], bh[4], al[4], bl[4];
#pragma unroll
    for (int mi = 0; mi < 4; ++mi) {
      const int row = wr + mi * 16 + fr;
      const int off = row * 32 + ((kb ^ (row & 3)) * 8);
      ah[mi] = *(const bf16x8*)&As_hi[off];
      if (AMODE == 2 && do_split) al[mi] = *(const bf16x8*)&As_lo[off];
    }
#pragma unroll
    for (int ni = 0; ni < 4; ++ni) {
      const int row = wc + ni * 16 + fr;
      const int off = row * 32 + ((kb ^ (row & 3)) * 8);
      bh[ni] = *(const bf16x8*)&Bs_hi[off];
      if (do_split) bl[ni] = *(const bf16x8*)&Bs_lo[off];
    }
#pragma unroll
    for (int mi = 0; mi < 4; ++mi)
#pragma unroll
      for (int ni = 0; ni < 4; ++ni) {
        acc[mi][ni] = __builtin_amdgcn_mfma_f32_16x16x32_bf16(ah[mi], bh[ni], acc[mi][ni], 0, 0, 0);
        if (do_split) {
          acc[mi][ni] = __builtin_amdgcn_mfma_f32_16x16x32_bf16(ah[mi], bl[ni], acc[mi][ni], 0, 0, 0);
          if (AMODE == 2)
            acc[mi][ni] = __builtin_amdgcn_mfma_f32_16x16x32_bf16(al[mi], bh[ni], acc[mi][ni], 0, 0, 0);
        }
      }
  }

  // ---- epilogue. C/D frag: col = lane&15, row = (lane>>4)*4 + r ----
#pragma unroll
  for (int mi = 0; mi < 4; ++mi)
#pragma unroll
    for (int ni = 0; ni < 4; ++ni) {
      const int gn = n0 + wc + ni * 16 + fr;
#pragma unroll
      for (int r = 0; r < 4; ++r) {
        const int gm = m0 + wr + mi * 16 + kb * 4 + r;
        const float v = acc[mi][ni][r];
        if (EPI == 0) {
          // proj col map: [X 0:4096 | A_dt 4096:4160 | B 4160:5184 | C 5184:6208 | gate 6208:10304]
          // conv_in = [X | B | C]  (6144 cols)
          if (gn < D_INNERC) {
            convin[(size_t)gm * CONV_DIMC + gn] = f2bf(v);
          } else if (gn < D_INNERC + NH) {
            A_dt[(size_t)gm * NH + (gn - D_INNERC)] = v;
          } else if (gn < D_INNERC + NH + 2 * GNC) {
            convin[(size_t)gm * CONV_DIMC + (gn - NH)] = f2bf(v);
          } else if (gn < IN_PROJC) {
            gate[(size_t)gm * D_INNERC + (gn - D_INNERC - NH - 2 * GNC)] = f2bf(v);
          }
        } else {
          Cout[(size_t)gm * ldc + gn] = v + res[(size_t)gm * ldc + gn];
        }
      }
    }
}

// ---------------- 3. depthwise conv(4, causal) + rmsnorm + silu (bf16 io) ----------------
__global__ __launch_bounds__(256) void conv_norm_kernel(
    const unsigned short* __restrict__ convin, const float* __restrict__ conv_w,
    const float* __restrict__ conv_b, const float* __restrict__ cnw,
    unsigned short* __restrict__ convout) {
  const int row = blockIdx.x;
  const int t = row & (SEQ - 1);
  const int tid = threadIdx.x;
  float vals[24];
  float ss = 0.f;
#pragma unroll
  for (int i = 0; i < 24; ++i) {
    const int c = tid + i * 256;
    float acc = conv_b[c];
    const float4 w4 = *(const float4*)(conv_w + c * 4);
    const float w_[4] = {w4.x, w4.y, w4.z, w4.w};
#pragma unroll
    for (int k = 0; k < 4; ++k) {
      const int tt = t - 3 + k;
      if (tt >= 0) acc += w_[k] * bf2f(convin[(size_t)(row - 3 + k) * CONV_DIMC + c]);
    }
    vals[i] = acc;
    ss += acc * acc;
  }
  ss = block_sum256(ss);
  const float rms = rsqrtf(ss * (1.0f / CONV_DIMC) + 1e-6f);
#pragma unroll
  for (int i = 0; i < 24; ++i) {
    const int c = tid + i * 256;
    convout[(size_t)row * CONV_DIMC + c] = f2bf(siluf(vals[i] * rms * cnw[c]));
  }
}

// ---------------- 4. dt/A ----------------
__global__ __launch_bounds__(64) void dt_kernel(
    const float* __restrict__ A_dt_buf, const float* __restrict__ dt_w,
    const float* __restrict__ dt_b, const float* __restrict__ A_log,
    float* __restrict__ Aarr) {
  const int row = blockIdx.x;
  const int h = threadIdx.x;
  __shared__ float ad[NH];
  ad[h] = A_dt_buf[(size_t)row * NH + h];
  __syncthreads();
  float s = dt_b[h];
  const float* wr = dt_w + h * NH;
#pragma unroll 8
  for (int j = 0; j < NH; ++j) s += ad[j] * wr[j];
  const float dt = (s > 20.f) ? s : log1pf(expf(s));
  const float a = -expf(A_log[h]) * dt;
  const int b = row >> 11;
  const int t = row & (SEQ - 1);
  const int c = t >> 8, tt = t & 255;
  Aarr[(((size_t)(b * NCHUNK + c) * NH + h) << 8) + tt] = a;  // [b][c][h][t]
}

// ---------------- 5. per-chunk inclusive cumsum ----------------
__global__ __launch_bounds__(256) void cumsum_kernel(
    const float* __restrict__ Aarr, float* __restrict__ Acs) {
  const size_t base = (size_t)blockIdx.x << 8;
  const int tid = threadIdx.x;
  __shared__ float s[CHUNKC];
  s[tid] = Aarr[base + tid];
  __syncthreads();
  for (int off = 1; off < CHUNKC; off <<= 1) {
    const float xv = (tid >= off) ? s[tid - off] : 0.f;
    __syncthreads();
    s[tid] += xv;
    __syncthreads();
  }
  Acs[base + tid] = s[tid];
}

// ---------------- 6. CB gram (bf16 io) ----------------
__global__ __launch_bounds__(256) void cb_kernel(
    const unsigned short* __restrict__ convout, unsigned short* __restrict__ CB) {
  const int bid = blockIdx.x;
  const int tq = bid & 3;
  const int g = (bid >> 2) & 7;
  const int c = (bid >> 5) & 7;
  const int b = bid >> 8;
  const int tid = threadIdx.x;
  const int t0 = tq * 64;
  const int tl = tid >> 2;
  const int s0 = (tid & 3) * 64;

  __shared__ float Cs[64][33];
  __shared__ float Bsh[256][33];

  float acc[64];
#pragma unroll
  for (int i = 0; i < 64; ++i) acc[i] = 0.f;
  const size_t rowbase = (size_t)(b * SEQ + c * CHUNKC) * CONV_DIMC;
  for (int n0 = 0; n0 < NST; n0 += 32) {
#pragma unroll
    for (int i = 0; i < 8; ++i) {
      const int idx = tid + i * 256;
      const int r = idx >> 5, nn = idx & 31;
      Cs[r][nn] = bf2f(convout[rowbase + (size_t)(t0 + r) * CONV_DIMC + D_INNERC + GNC + g * NST + n0 + nn]);
    }
#pragma unroll
    for (int i = 0; i < 32; ++i) {
      const int idx = tid + i * 256;
      const int r = idx >> 5, nn = idx & 31;
      Bsh[r][nn] = bf2f(convout[rowbase + (size_t)r * CONV_DIMC + D_INNERC + g * NST + n0 + nn]);
    }
    __syncthreads();
    for (int nn = 0; nn < 32; ++nn) {
      const float cv = Cs[tl][nn];
#pragma unroll
      for (int ssi = 0; ssi < 64; ++ssi) acc[ssi] += cv * Bsh[s0 + ssi][nn];
    }
    __syncthreads();
  }
  unsigned short* cbp = CB + ((size_t)((b * NCHUNK + c) * NG + g) << 16) + (size_t)(t0 + tl) * CHUNKC + s0;
#pragma unroll
  for (int ssi = 0; ssi < 64; ++ssi) cbp[ssi] = f2bf(acc[ssi]);
}

// ---------------- 7. chunk states (bf16 in, fp32 out) ----------------
__global__ __launch_bounds__(256) void states_kernel(
    const unsigned short* __restrict__ convout, const float* __restrict__ Acs,
    float* __restrict__ states) {
  const int bid = blockIdx.x;
  const int h = bid & 63;
  const int c = (bid >> 6) & 7;
  const int b = bid >> 9;
  const int g = h >> 3;
  const int tid = threadIdx.x;

  __shared__ float Bt[64][NST];
  __shared__ float Xt[64][DHEAD + 1];
  __shared__ float acs_s[CHUNKC];

  acs_s[tid] = Acs[((size_t)bid << 8) + tid];
  __syncthreads();
  const float A_last = acs_s[CHUNKC - 1];

  const int n0 = (tid >> 3) * 4;
  const int d0 = (tid & 7) * 8;
  float acc[4][8];
#pragma unroll
  for (int i = 0; i < 4; ++i)
#pragma unroll
    for (int j = 0; j < 8; ++j) acc[i][j] = 0.f;

  const size_t rowbase = (size_t)(b * SEQ + c * CHUNKC) * CONV_DIMC;
  for (int t0 = 0; t0 < CHUNKC; t0 += 64) {
#pragma unroll
    for (int i = 0; i < 32; ++i) {
      const int idx = tid + i * 256;
      const int r = idx >> 7, col = idx & 127;
      Bt[r][col] = bf2f(convout[rowbase + (size_t)(t0 + r) * CONV_DIMC + D_INNERC + g * NST + col]);
    }
#pragma unroll
    for (int i = 0; i < 16; ++i) {
      const int idx = tid + i * 256;
      const int r = idx >> 6, d = idx & 63;
      Xt[r][d] = bf2f(convout[rowbase + (size_t)(t0 + r) * CONV_DIMC + h * DHEAD + d]) *
                 expf(A_last - acs_s[t0 + r]);
    }
    __syncthreads();
    for (int tt = 0; tt < 64; ++tt) {
      float bv[4], xv[8];
#pragma unroll
      for (int i = 0; i < 4; ++i) bv[i] = Bt[tt][n0 + i];
#pragma unroll
      for (int j = 0; j < 8; ++j) xv[j] = Xt[tt][d0 + j];
#pragma unroll
      for (int i = 0; i < 4; ++i)
#pragma unroll
        for (int j = 0; j < 8; ++j) acc[i][j] += bv[i] * xv[j];
    }
    __syncthreads();
  }
  float* sp = states + ((size_t)bid << 13);
#pragma unroll
  for (int i = 0; i < 4; ++i)
#pragma unroll
    for (int j = 0; j < 8; ++j) sp[(n0 + i) * DHEAD + d0 + j] = acc[i][j];
}

// ---------------- 8. sequential chunk scan (fp32, h_prev in place) ----------------
__global__ __launch_bounds__(256) void chunkscan_kernel(
    float* __restrict__ states_hprev, const float* __restrict__ Acs,
    float* __restrict__ hfinal) {
  const size_t i = (size_t)blockIdx.x * 256 + threadIdx.x;
  const int b = (int)(i >> 19);
  const int h = (int)((i >> 13) & 63);
  const int nd = (int)(i & 8191);
  float hv = 0.f;
#pragma unroll
  for (int c = 0; c < NCHUNK; ++c) {
    const int bch = (b * NCHUNK + c) * NH + h;
    const size_t sidx = ((size_t)bch << 13) + nd;
    const float st = states_hprev[sidx];
    const float cd = expf(Acs[((size_t)bch << 8) + 255]);
    states_hprev[sidx] = hv;
    hv = hv * cd + st;
  }
  hfinal[((size_t)(b * NH + h) << 13) + nd] = hv;
}

// ---------------- 9. Y = diag + carry (bf16 out, [4096][4096]) ----------------
__global__ __launch_bounds__(256) void y_kernel(
    const unsigned short* __restrict__ convout, const float* __restrict__ Acs,
    const unsigned short* __restrict__ CB, const float* __restrict__ hprev,
    unsigned short* __restrict__ Ybuf) {
  const int bid = blockIdx.x;
  const int h = bid & 63;
  const int c = (bid >> 6) & 7;
  const int b = bid >> 9;
  const int g = h >> 3;
  const int t = threadIdx.x;

  __shared__ float hs[NST][DHEAD];
  __shared__ float xs[64][DHEAD];
  __shared__ float acs_s[CHUNKC];

  acs_s[t] = Acs[((size_t)bid << 8) + t];
  {
    const float* hp = hprev + ((size_t)bid << 13);
#pragma unroll
    for (int i = 0; i < 32; ++i) {
      const int idx = t + i * 256;
      ((float*)hs)[idx] = hp[idx];
    }
  }
  __syncthreads();

  float4 acc[16];
#pragma unroll
  for (int i = 0; i < 16; ++i) acc[i] = make_float4(0.f, 0.f, 0.f, 0.f);

  const size_t rowbase = (size_t)(b * SEQ + c * CHUNKC) * CONV_DIMC;
  // carry: C[t]·h_prev
  const unsigned short* c16 = convout + rowbase + (size_t)t * CONV_DIMC + D_INNERC + GNC + g * NST;
  for (int n4 = 0; n4 < 32; ++n4) {
    const uint2 cq = *(const uint2*)(c16 + n4 * 4);
    const float cv_[4] = {bf2f((unsigned short)(cq.x & 0xffff)), bf2f((unsigned short)(cq.x >> 16)),
                          bf2f((unsigned short)(cq.y & 0xffff)), bf2f((unsigned short)(cq.y >> 16))};
#pragma unroll
    for (int l = 0; l < 4; ++l) {
      const float cv = cv_[l];
      const float4* hr = (const float4*)hs[n4 * 4 + l];
#pragma unroll
      for (int j = 0; j < 16; ++j) {
        const float4 hv = hr[j];
        acc[j].x += cv * hv.x; acc[j].y += cv * hv.y;
        acc[j].z += cv * hv.z; acc[j].w += cv * hv.w;
      }
    }
  }
  const float at = acs_s[t];
  const float ea = expf(at);
#pragma unroll
  for (int j = 0; j < 16; ++j) {
    acc[j].x *= ea; acc[j].y *= ea; acc[j].z *= ea; acc[j].w *= ea;
  }
  // diagonal
  const unsigned short* cbrow = CB + ((size_t)((b * NCHUNK + c) * NG + g) << 16) + (size_t)t * CHUNKC;
  for (int s0 = 0; s0 < CHUNKC; s0 += 64) {
    __syncthreads();
#pragma unroll
    for (int i = 0; i < 16; ++i) {
      const int idx = t + i * 256;
      const int r = idx >> 6, d = idx & 63;
      xs[r][d] = bf2f(convout[rowbase + (size_t)(s0 + r) * CONV_DIMC + h * DHEAD + d]);
    }
    __syncthreads();
    if (s0 <= t) {
      const int smax = min(64, t - s0 + 1);
      for (int ssi = 0; ssi < smax; ++ssi) {
        const float w = expf(at - acs_s[s0 + ssi]) * bf2f(cbrow[s0 + ssi]);
        const float4* xr = (const float4*)xs[ssi];
#pragma unroll
        for (int j = 0; j < 16; ++j) {
          const float4 xv = xr[j];
          acc[j].x += w * xv.x; acc[j].y += w * xv.y;
          acc[j].z += w * xv.z; acc[j].w += w * xv.w;
        }
      }
    }
  }
  unsigned* yp = (unsigned*)(Ybuf + (size_t)(b * SEQ + c * CHUNKC + t) * D_INNERC + h * DHEAD);
#pragma unroll
  for (int j = 0; j < 16; ++j) {
    yp[2 * j]     = (unsigned)f2bf(acc[j].x) | ((unsigned)f2bf(acc[j].y) << 16);
    yp[2 * j + 1] = (unsigned)f2bf(acc[j].z) | ((unsigned)f2bf(acc[j].w) << 16);
  }
}

// ---------------- 10. out-norm * silu(gate), in place on Y bf16 ----------------
__global__ __launch_bounds__(256) void ynorm_kernel(
    unsigned short* __restrict__ Ybuf, const unsigned short* __restrict__ gate,
    const float* __restrict__ onw) {
  const int row = blockIdx.x;
  const int tid = threadIdx.x;
  unsigned short* yrow = Ybuf + (size_t)row * D_INNERC;
  const unsigned short* grow = gate + (size_t)row * D_INNERC;
  float v[16];
  float ss = 0.f;
#pragma unroll
  for (int i = 0; i < 2; ++i) {
    const int g8 = tid + i * 256;  // group of 8 bf16
    const uint4 q = ((const uint4*)yrow)[g8];
    const unsigned qq[4] = {q.x, q.y, q.z, q.w};
#pragma unroll
    for (int j = 0; j < 4; ++j) {
      const float a = bf2f((unsigned short)(qq[j] & 0xffff));
      const float bb = bf2f((unsigned short)(qq[j] >> 16));
      v[i * 8 + 2 * j] = a;
      v[i * 8 + 2 * j + 1] = bb;
      ss += a * a + bb * bb;
    }
  }
  ss = block_sum256(ss);
  const float rms = rsqrtf(ss * (1.0f / D_INNERC) + 1e-6f);
#pragma unroll
  for (int i = 0; i < 2; ++i) {
    const int g8 = tid + i * 256;
    const uint4 gq = ((const uint4*)grow)[g8];
    const unsigned gg[4] = {gq.x, gq.y, gq.z, gq.w};
    const float4 w0 = ((const float4*)onw)[g8 * 2];
    const float4 w1 = ((const float4*)onw)[g8 * 2 + 1];
    const float w_[8] = {w0.x, w0.y, w0.z, w0.w, w1.x, w1.y, w1.z, w1.w};
    uint4 o;
    unsigned oo[4];
#pragma unroll
    for (int j = 0; j < 4; ++j) {
      const float ga = siluf(bf2f((unsigned short)(gg[j] & 0xffff)));
      const float gb = siluf(bf2f((unsigned short)(gg[j] >> 16)));
      const float ya = v[i * 8 + 2 * j] * rms * w_[2 * j] * ga;
      const float yb = v[i * 8 + 2 * j + 1] * rms * w_[2 * j + 1] * gb;
      oo[j] = (unsigned)f2bf(ya) | ((unsigned)f2bf(yb) << 16);
    }
    o.x = oo[0]; o.y = oo[1]; o.z = oo[2]; o.w = oo[3];
    ((uint4*)yrow)[g8] = o;
  }
}

extern "C" void kernel_launch(void* const* d_in, const int* in_sizes, int n_in,
                              void* d_out, int out_size, void* d_ws, size_t ws_size,
                              hipStream_t stream) {
  const float* x           = (const float*)d_in[0];
  const float* norm_w      = (const float*)d_in[1];
  const float* in_proj_w   = (const float*)d_in[2];
  const float* conv_w      = (const float*)d_in[3];
  const float* conv_b      = (const float*)d_in[4];
  const float* conv_norm_w = (const float*)d_in[5];
  const float* A_log       = (const float*)d_in[6];
  const float* dt_w        = (const float*)d_in[7];
  const float* dt_b        = (const float*)d_in[8];
  const float* out_norm_w  = (const float*)d_in[9];
  const float* out_proj_w  = (const float*)d_in[10];
  float* out = (float*)d_out;
  char* base = (char*)d_ws;

  // ws layout (bytes), total 204,472,320:
  //   [0,            50331648)  convin bf16 [4096][6144]; later aliased: Y bf16 [4096][4096]
  //   [50331648,    100663296)  convout bf16 [4096][6144]
  //   [100663296,   134217728)  gate bf16 [4096][4096]
  //   [134217728,   150994944)  xn_hi bf16 [4096][2048]; later aliased: CB bf16 (16.8 MB)
  //   [150994944,   167772160)  xn_lo bf16 [4096][2048]
  //   [167772160,   201326592)  states fp32 (h_prev in place)
  //   [201326592,   202375168)  A_dt fp32 [4096][64]
  //   [202375168,   203423744)  Aarr fp32
  //   [203423744,   204472320)  Acs fp32
  unsigned short* convin  = (unsigned short*)(base);
  unsigned short* Ybuf    = (unsigned short*)(base);                // alias (convin dead)
  unsigned short* convout = (unsigned short*)(base + 50331648ull);
  unsigned short* gate    = (unsigned short*)(base + 100663296ull);
  unsigned short* xnhi    = (unsigned short*)(base + 134217728ull);
  unsigned short* CBbuf   = (unsigned short*)(base + 134217728ull); // alias (xn dead)
  unsigned short* xnlo    = (unsigned short*)(base + 150994944ull);
  float*          states  = (float*)(base + 167772160ull);
  float*          A_dt    = (float*)(base + 201326592ull);
  float*          Aarr    = (float*)(base + 202375168ull);
  float*          Acs     = (float*)(base + 203423744ull);

  if (ws_size < 204472320ull) return;  // fail-clean signature: Output0 err == 5.9375

  float* hfinal = out + 8388608ull;

  rmsnorm_in_kernel<<<ROWS, 256, 0, stream>>>(x, norm_w, xnhi, xnlo);
  // GEMM1: A = bf16 hi/lo planes, W split (gate blocks demoted), proj-routing epilogue
  mfma_gemm<2, true, 0><<<dim3(ROWS / 128, (IN_PROJC + 127) / 128), 256, 0, stream>>>(
      xnhi, xnlo, D_MODELC, in_proj_w, IN_PROJC, D_MODELC,
      convin, A_dt, gate, nullptr, nullptr, 0);
  conv_norm_kernel<<<ROWS, 256, 0, stream>>>(convin, conv_w, conv_b, conv_norm_w, convout);
  dt_kernel<<<ROWS, 64, 0, stream>>>(A_dt, dt_w, dt_b, A_log, Aarr);
  cumsum_kernel<<<BATCH * NCHUNK * NH, 256, 0, stream>>>(Aarr, Acs);
  cb_kernel<<<BATCH * NCHUNK * NG * 4, 256, 0, stream>>>(convout, CBbuf);
  states_kernel<<<BATCH * NCHUNK * NH, 256, 0, stream>>>(convout, Acs, states);
  chunkscan_kernel<<<4096, 256, 0, stream>>>(states, Acs, hfinal);
  y_kernel<<<BATCH * NCHUNK * NH, 256, 0, stream>>>(convout, Acs, CBbuf, states, Ybuf);
  ynorm_kernel<<<ROWS, 256, 0, stream>>>(Ybuf, gate, out_norm_w);
  // GEMM2: A = Ybuf bf16 single-plane, plain bf16 W, + residual
  mfma_gemm<1, false, 1><<<dim3(ROWS / 128, D_MODELC / 128), 256, 0, stream>>>(
      Ybuf, nullptr, D_INNERC, out_proj_w, D_MODELC, D_INNERC,
      nullptr, nullptr, nullptr, out, x, D_MODELC);
}

// Round 7
// 1500.103 us; speedup vs baseline: 1.3270x; 1.3270x over previous
//
#include <hip/hip_runtime.h>
#include <math.h>

// ---- problem constants ----
#define D_MODELC 2048
#define D_INNERC 4096
#define NH 64        // H heads
#define DHEAD 64     // D_HEAD
#define NST 128      // N state dim
#define NG 8         // G groups
#define CHUNKC 256
#define GNC 1024     // G*N
#define CONV_DIMC 6144
#define IN_PROJC 10304
#define BATCH 2
#define SEQ 2048
#define NCHUNK 8
#define ROWS 4096
// proj column map: [X 0:4096 | A_dt 4096:4160 | B 4160:5184 | C 5184:6208 | gate 6208:10304]

typedef __attribute__((ext_vector_type(8))) short bf16x8;
typedef __attribute__((ext_vector_type(4))) float f32x4;

__device__ __forceinline__ float bf2f(unsigned short h) {
  return __uint_as_float(((unsigned)h) << 16);
}
__device__ __forceinline__ unsigned short f2bf(float f) {
  unsigned u = __float_as_uint(f);
  u += 0x7FFFu + ((u >> 16) & 1u);   // round-to-nearest-even
  return (unsigned short)(u >> 16);
}
// HW packed conversion: dst.lo16 = bf16(a), dst.hi16 = bf16(b)
__device__ __forceinline__ unsigned cvtpk(float a, float b) {
  unsigned r;
  asm("v_cvt_pk_bf16_f32 %0, %1, %2" : "=v"(r) : "v"(a), "v"(b));
  return r;
}
__device__ __forceinline__ uint4 pack8_cvt(const float* f) {
  uint4 r;
  r.x = cvtpk(f[0], f[1]); r.y = cvtpk(f[2], f[3]);
  r.z = cvtpk(f[4], f[5]); r.w = cvtpk(f[6], f[7]);
  return r;
}
__device__ __forceinline__ void resid8(const float* f, uint4 q, float* lo) {
  lo[0] = f[0] - __uint_as_float(q.x << 16);
  lo[1] = f[1] - __uint_as_float(q.x & 0xffff0000u);
  lo[2] = f[2] - __uint_as_float(q.y << 16);
  lo[3] = f[3] - __uint_as_float(q.y & 0xffff0000u);
  lo[4] = f[4] - __uint_as_float(q.z << 16);
  lo[5] = f[5] - __uint_as_float(q.z & 0xffff0000u);
  lo[6] = f[6] - __uint_as_float(q.w << 16);
  lo[7] = f[7] - __uint_as_float(q.w & 0xffff0000u);
}
__device__ __forceinline__ float siluf(float x) { return x / (1.0f + expf(-x)); }

// async global->LDS, 16 bytes per lane; LDS dest must be wave-uniform base
__device__ __forceinline__ void gload16(const unsigned short* g, unsigned short* l) {
  __builtin_amdgcn_global_load_lds(
      (const __attribute__((address_space(1))) void*)g,
      (__attribute__((address_space(3))) void*)l, 16, 0, 0);
}

__device__ __forceinline__ float block_sum256(float v) {
#pragma unroll
  for (int off = 32; off > 0; off >>= 1) v += __shfl_down(v, off, 64);
  __shared__ float red[4];
  const int lane = threadIdx.x & 63, wv = threadIdx.x >> 6;
  if (lane == 0) red[wv] = v;
  __syncthreads();
  float s = red[0] + red[1] + red[2] + red[3];
  __syncthreads();
  return s;
}

// ---------------- 0. W fp32 -> bf16(hi) plane ----------------
__global__ __launch_bounds__(256) void wconv_kernel(
    const float* __restrict__ W, unsigned short* __restrict__ Whi,
    int n_valid, int n_total) {
  const int i = (blockIdx.x * 256 + threadIdx.x) * 8;
  if (i >= n_total) return;
  float v[8];
  if (i + 8 <= n_valid) {
    *(float4*)&v[0] = *(const float4*)(W + i);
    *(float4*)&v[4] = *(const float4*)(W + i + 4);
  } else {
#pragma unroll
    for (int j = 0; j < 8; ++j) v[j] = 0.f;
  }
  *(uint4*)&Whi[i] = pack8_cvt(v);
}

// ---------------- 1. input rmsnorm -> bf16 hi/lo planes ----------------
__global__ __launch_bounds__(256) void rmsnorm_in_kernel(
    const float* __restrict__ x, const float* __restrict__ nw,
    unsigned short* __restrict__ xnhi, unsigned short* __restrict__ xnlo) {
  const int row = blockIdx.x;
  const int tid = threadIdx.x;
  const float4* xr = (const float4*)(x + (size_t)row * D_MODELC);
  float4 v[2];
  float ss = 0.f;
#pragma unroll
  for (int i = 0; i < 2; ++i) {
    v[i] = xr[tid + i * 256];
    ss += v[i].x * v[i].x + v[i].y * v[i].y + v[i].z * v[i].z + v[i].w * v[i].w;
  }
  ss = block_sum256(ss);
  const float rms = rsqrtf(ss * (1.0f / D_MODELC) + 1e-6f);
  const float4* wp = (const float4*)nw;
#pragma unroll
  for (int i = 0; i < 2; ++i) {
    const int idx = tid + i * 256;
    const float4 w4 = wp[idx];
    float a = v[i].x * rms * w4.x;
    float b = v[i].y * rms * w4.y;
    float c = v[i].z * rms * w4.z;
    float d = v[i].w * rms * w4.w;
    unsigned h0 = cvtpk(a, b), h1 = cvtpk(c, d);
    float la = a - __uint_as_float(h0 << 16);
    float lb = b - __uint_as_float(h0 & 0xffff0000u);
    float lc = c - __uint_as_float(h1 << 16);
    float ld = d - __uint_as_float(h1 & 0xffff0000u);
    unsigned l0 = cvtpk(la, lb), l1 = cvtpk(lc, ld);
    *(uint2*)&xnhi[(size_t)row * D_MODELC + idx * 4] = make_uint2(h0, h1);
    *(uint2*)&xnlo[(size_t)row * D_MODELC + idx * 4] = make_uint2(l0, l1);
  }
}

// ---------------- 2a. FAST MFMA GEMM (pure bf16, global_load_lds staging) ----------------
// C[M,N] = A[M,K]bf16 @ Wq[N,K]bf16^T.  EPI==0: proj routing (skips blockIdx.y==skipy);
// EPI==1: Cout = acc + res.
template <int EPI>
__global__ __launch_bounds__(256) void mfma_gemm_fast(
    const unsigned short* __restrict__ Ahi, int lda,
    const unsigned short* __restrict__ Wq, int K, int skipy,
    unsigned short* __restrict__ convin, float* __restrict__ A_dt,
    unsigned short* __restrict__ gate,
    float* __restrict__ Cout, const float* __restrict__ res, int ldc) {
  __shared__ __align__(16) unsigned short As[128 * 32];
  __shared__ __align__(16) unsigned short Ws[128 * 32];
  if (EPI == 0 && (int)blockIdx.y == skipy) return;

  const int tid = threadIdx.x;
  const int m0 = blockIdx.x * 128;
  const int n0 = blockIdx.y * 128;
  const int lane = tid & 63, wv = tid >> 6;
  const int wr = (wv >> 1) * 64, wc = (wv & 1) * 64;
  const int fr = lane & 15, kb = lane >> 4;

  // staging map: thread t covers row t>>2, cols (t&3)*8 .. +7 (16B)
  const int arow = tid >> 2, acol = (tid & 3) * 8;
  const unsigned short* ga0 = Ahi + (size_t)(m0 + arow) * lda + acol;
  const unsigned short* ga1 = ga0 + (size_t)64 * lda;
  const unsigned short* gw0 = Wq + (size_t)(n0 + arow) * K + acol;
  const unsigned short* gw1 = gw0 + (size_t)64 * K;
  unsigned short* la0 = &As[(tid >> 6) * 512];          // wave-uniform LDS bases
  unsigned short* la1 = &As[2048 + (tid >> 6) * 512];
  unsigned short* lw0 = &Ws[(tid >> 6) * 512];
  unsigned short* lw1 = &Ws[2048 + (tid >> 6) * 512];

  f32x4 acc[4][4];
#pragma unroll
  for (int i = 0; i < 4; ++i)
#pragma unroll
    for (int j = 0; j < 4; ++j) acc[i][j] = (f32x4){0.f, 0.f, 0.f, 0.f};

  for (int k0 = 0; k0 < K; k0 += 32) {
    __syncthreads();                   // prev iter's ds_reads done
    gload16(ga0 + k0, la0);
    gload16(ga1 + k0, la1);
    gload16(gw0 + k0, lw0);
    gload16(gw1 + k0, lw1);
    __syncthreads();                   // drains vmcnt; LDS visible

    bf16x8 ah[4], bh[4];
#pragma unroll
    for (int mi = 0; mi < 4; ++mi)
      ah[mi] = *(const bf16x8*)&As[(wr + mi * 16 + fr) * 32 + kb * 8];
#pragma unroll
    for (int ni = 0; ni < 4; ++ni)
      bh[ni] = *(const bf16x8*)&Ws[(wc + ni * 16 + fr) * 32 + kb * 8];
#pragma unroll
    for (int mi = 0; mi < 4; ++mi)
#pragma unroll
      for (int ni = 0; ni < 4; ++ni)
        acc[mi][ni] = __builtin_amdgcn_mfma_f32_16x16x32_bf16(ah[mi], bh[ni], acc[mi][ni], 0, 0, 0);
  }

  // epilogue. C/D frag: col = lane&15, row = (lane>>4)*4 + r
#pragma unroll
  for (int mi = 0; mi < 4; ++mi)
#pragma unroll
    for (int ni = 0; ni < 4; ++ni) {
      const int gn = n0 + wc + ni * 16 + fr;
#pragma unroll
      for (int r = 0; r < 4; ++r) {
        const int gm = m0 + wr + mi * 16 + kb * 4 + r;
        const float v = acc[mi][ni][r];
        if (EPI == 0) {
          if (gn < D_INNERC) {
            convin[(size_t)gm * CONV_DIMC + gn] = f2bf(v);
          } else if (gn < D_INNERC + NH) {
            A_dt[(size_t)gm * NH + (gn - D_INNERC)] = v;
          } else if (gn < D_INNERC + NH + 2 * GNC) {
            convin[(size_t)gm * CONV_DIMC + (gn - NH)] = f2bf(v);
          } else if (gn < IN_PROJC) {
            gate[(size_t)gm * D_INNERC + (gn - D_INNERC - NH - 2 * GNC)] = f2bf(v);
          }
        } else {
          Cout[(size_t)gm * ldc + gn] = v + res[(size_t)gm * ldc + gn];
        }
      }
    }
}

// ---------------- 2b. SPLIT MFMA GEMM (register staging, hi/lo, 3 MFMA) ----------------
// Used only for the A_dt-containing N-block (ybase=32): accuracy-critical dt path.
__global__ __launch_bounds__(256) void mfma_gemm_split(
    const unsigned short* __restrict__ Ahi, const unsigned short* __restrict__ Alo, int lda,
    const float* __restrict__ W, int N, int K, int ybase,
    unsigned short* __restrict__ convin, float* __restrict__ A_dt,
    unsigned short* __restrict__ gate) {
  __shared__ unsigned short As_hi[128 * 32];
  __shared__ unsigned short Bs_hi[128 * 32];
  __shared__ unsigned short As_lo[128 * 32];
  __shared__ unsigned short Bs_lo[128 * 32];

  const int tid = threadIdx.x;
  const int m0 = blockIdx.x * 128;
  const int n0 = (blockIdx.y + ybase) * 128;
  const int lane = tid & 63, wv = tid >> 6;
  const int wr = (wv >> 1) * 64, wc = (wv & 1) * 64;
  const int fr = lane & 15, kb = lane >> 4;
  const int srow = tid >> 1;
  const int shalf = tid & 1;

  f32x4 acc[4][4];
#pragma unroll
  for (int i = 0; i < 4; ++i)
#pragma unroll
    for (int j = 0; j < 4; ++j) acc[i][j] = (f32x4){0.f, 0.f, 0.f, 0.f};

  const int c0s = (shalf * 2) ^ (srow & 3);
  const int c1s = (shalf * 2 + 1) ^ (srow & 3);
  const int wbase = srow * 32;

  for (int k0 = 0; k0 < K; k0 += 32) {
    __syncthreads();
    {
      const unsigned short* sh = Ahi + (size_t)(m0 + srow) * lda + k0 + shalf * 16;
      *(uint4*)&As_hi[wbase + c0s * 8] = *(const uint4*)(sh);
      *(uint4*)&As_hi[wbase + c1s * 8] = *(const uint4*)(sh + 8);
      const unsigned short* sl = Alo + (size_t)(m0 + srow) * lda + k0 + shalf * 16;
      *(uint4*)&As_lo[wbase + c0s * 8] = *(const uint4*)(sl);
      *(uint4*)&As_lo[wbase + c1s * 8] = *(const uint4*)(sl + 8);
    }
    {
      const int gn = n0 + srow;
      float v[16];
      const float* src = W + (size_t)gn * K + k0 + shalf * 16;
      *(float4*)&v[0] = *(const float4*)(src);
      *(float4*)&v[4] = *(const float4*)(src + 4);
      *(float4*)&v[8] = *(const float4*)(src + 8);
      *(float4*)&v[12] = *(const float4*)(src + 12);
      uint4 qh0 = pack8_cvt(&v[0]);
      uint4 qh1 = pack8_cvt(&v[8]);
      *(uint4*)&Bs_hi[wbase + c0s * 8] = qh0;
      *(uint4*)&Bs_hi[wbase + c1s * 8] = qh1;
      float lo[16];
      resid8(&v[0], qh0, &lo[0]);
      resid8(&v[8], qh1, &lo[8]);
      *(uint4*)&Bs_lo[wbase + c0s * 8] = pack8_cvt(&lo[0]);
      *(uint4*)&Bs_lo[wbase + c1s * 8] = pack8_cvt(&lo[8]);
    }
    __syncthreads();

    bf16x8 ah[4], bh[4], al[4], bl[4];
#pragma unroll
    for (int mi = 0; mi < 4; ++mi) {
      const int row = wr + mi * 16 + fr;
      const int off = row * 32 + ((kb ^ (row & 3)) * 8);
      ah[mi] = *(const bf16x8*)&As_hi[off];
      al[mi] = *(const bf16x8*)&As_lo[off];
    }
#pragma unroll
    for (int ni = 0; ni < 4; ++ni) {
      const int row = wc + ni * 16 + fr;
      const int off = row * 32 + ((kb ^ (row & 3)) * 8);
      bh[ni] = *(const bf16x8*)&Bs_hi[off];
      bl[ni] = *(const bf16x8*)&Bs_lo[off];
    }
#pragma unroll
    for (int mi = 0; mi < 4; ++mi)
#pragma unroll
      for (int ni = 0; ni < 4; ++ni) {
        acc[mi][ni] = __builtin_amdgcn_mfma_f32_16x16x32_bf16(ah[mi], bh[ni], acc[mi][ni], 0, 0, 0);
        acc[mi][ni] = __builtin_amdgcn_mfma_f32_16x16x32_bf16(ah[mi], bl[ni], acc[mi][ni], 0, 0, 0);
        acc[mi][ni] = __builtin_amdgcn_mfma_f32_16x16x32_bf16(al[mi], bh[ni], acc[mi][ni], 0, 0, 0);
      }
  }

#pragma unroll
  for (int mi = 0; mi < 4; ++mi)
#pragma unroll
    for (int ni = 0; ni < 4; ++ni) {
      const int gn = n0 + wc + ni * 16 + fr;
#pragma unroll
      for (int r = 0; r < 4; ++r) {
        const int gm = m0 + wr + mi * 16 + kb * 4 + r;
        const float v = acc[mi][ni][r];
        if (gn < D_INNERC) {
          convin[(size_t)gm * CONV_DIMC + gn] = f2bf(v);
        } else if (gn < D_INNERC + NH) {
          A_dt[(size_t)gm * NH + (gn - D_INNERC)] = v;
        } else if (gn < D_INNERC + NH + 2 * GNC) {
          convin[(size_t)gm * CONV_DIMC + (gn - NH)] = f2bf(v);
        } else if (gn < IN_PROJC) {
          gate[(size_t)gm * D_INNERC + (gn - D_INNERC - NH - 2 * GNC)] = f2bf(v);
        }
      }
    }
}

// ---------------- 3. depthwise conv(4, causal) + rmsnorm + silu (bf16 io) ----------------
__global__ __launch_bounds__(256) void conv_norm_kernel(
    const unsigned short* __restrict__ convin, const float* __restrict__ conv_w,
    const float* __restrict__ conv_b, const float* __restrict__ cnw,
    unsigned short* __restrict__ convout) {
  const int row = blockIdx.x;
  const int t = row & (SEQ - 1);
  const int tid = threadIdx.x;
  float vals[24];
  float ss = 0.f;
#pragma unroll
  for (int i = 0; i < 24; ++i) {
    const int c = tid + i * 256;
    float acc = conv_b[c];
    const float4 w4 = *(const float4*)(conv_w + c * 4);
    const float w_[4] = {w4.x, w4.y, w4.z, w4.w};
#pragma unroll
    for (int k = 0; k < 4; ++k) {
      const int tt = t - 3 + k;
      if (tt >= 0) acc += w_[k] * bf2f(convin[(size_t)(row - 3 + k) * CONV_DIMC + c]);
    }
    vals[i] = acc;
    ss += acc * acc;
  }
  ss = block_sum256(ss);
  const float rms = rsqrtf(ss * (1.0f / CONV_DIMC) + 1e-6f);
#pragma unroll
  for (int i = 0; i < 24; ++i) {
    const int c = tid + i * 256;
    convout[(size_t)row * CONV_DIMC + c] = f2bf(siluf(vals[i] * rms * cnw[c]));
  }
}

// ---------------- 4. dt/A ----------------
__global__ __launch_bounds__(64) void dt_kernel(
    const float* __restrict__ A_dt_buf, const float* __restrict__ dt_w,
    const float* __restrict__ dt_b, const float* __restrict__ A_log,
    float* __restrict__ Aarr) {
  const int row = blockIdx.x;
  const int h = threadIdx.x;
  __shared__ float ad[NH];
  ad[h] = A_dt_buf[(size_t)row * NH + h];
  __syncthreads();
  float s = dt_b[h];
  const float* wr = dt_w + h * NH;
#pragma unroll 8
  for (int j = 0; j < NH; ++j) s += ad[j] * wr[j];
  const float dt = (s > 20.f) ? s : log1pf(expf(s));
  const float a = -expf(A_log[h]) * dt;
  const int b = row >> 11;
  const int t = row & (SEQ - 1);
  const int c = t >> 8, tt = t & 255;
  Aarr[(((size_t)(b * NCHUNK + c) * NH + h) << 8) + tt] = a;  // [b][c][h][t]
}

// ---------------- 5. per-chunk inclusive cumsum ----------------
__global__ __launch_bounds__(256) void cumsum_kernel(
    const float* __restrict__ Aarr, float* __restrict__ Acs) {
  const size_t base = (size_t)blockIdx.x << 8;
  const int tid = threadIdx.x;
  __shared__ float s[CHUNKC];
  s[tid] = Aarr[base + tid];
  __syncthreads();
  for (int off = 1; off < CHUNKC; off <<= 1) {
    const float xv = (tid >= off) ? s[tid - off] : 0.f;
    __syncthreads();
    s[tid] += xv;
    __syncthreads();
  }
  Acs[base + tid] = s[tid];
}

// ---------------- 6. CB gram (bf16 io) ----------------
__global__ __launch_bounds__(256) void cb_kernel(
    const unsigned short* __restrict__ convout, unsigned short* __restrict__ CB) {
  const int bid = blockIdx.x;
  const int tq = bid & 3;
  const int g = (bid >> 2) & 7;
  const int c = (bid >> 5) & 7;
  const int b = bid >> 8;
  const int tid = threadIdx.x;
  const int t0 = tq * 64;
  const int tl = tid >> 2;
  const int s0 = (tid & 3) * 64;

  __shared__ float Cs[64][33];
  __shared__ float Bsh[256][33];

  float acc[64];
#pragma unroll
  for (int i = 0; i < 64; ++i) acc[i] = 0.f;
  const size_t rowbase = (size_t)(b * SEQ + c * CHUNKC) * CONV_DIMC;
  for (int n0 = 0; n0 < NST; n0 += 32) {
#pragma unroll
    for (int i = 0; i < 8; ++i) {
      const int idx = tid + i * 256;
      const int r = idx >> 5, nn = idx & 31;
      Cs[r][nn] = bf2f(convout[rowbase + (size_t)(t0 + r) * CONV_DIMC + D_INNERC + GNC + g * NST + n0 + nn]);
    }
#pragma unroll
    for (int i = 0; i < 32; ++i) {
      const int idx = tid + i * 256;
      const int r = idx >> 5, nn = idx & 31;
      Bsh[r][nn] = bf2f(convout[rowbase + (size_t)r * CONV_DIMC + D_INNERC + g * NST + n0 + nn]);
    }
    __syncthreads();
    for (int nn = 0; nn < 32; ++nn) {
      const float cv = Cs[tl][nn];
#pragma unroll
      for (int ssi = 0; ssi < 64; ++ssi) acc[ssi] += cv * Bsh[s0 + ssi][nn];
    }
    __syncthreads();
  }
  unsigned short* cbp = CB + ((size_t)((b * NCHUNK + c) * NG + g) << 16) + (size_t)(t0 + tl) * CHUNKC + s0;
#pragma unroll
  for (int ssi = 0; ssi < 64; ++ssi) cbp[ssi] = f2bf(acc[ssi]);
}

// ---------------- 7. chunk states (bf16 in, fp32 out) ----------------
__global__ __launch_bounds__(256) void states_kernel(
    const unsigned short* __restrict__ convout, const float* __restrict__ Acs,
    float* __restrict__ states) {
  const int bid = blockIdx.x;
  const int h = bid & 63;
  const int c = (bid >> 6) & 7;
  const int b = bid >> 9;
  const int g = h >> 3;
  const int tid = threadIdx.x;

  __shared__ float Bt[64][NST];
  __shared__ float Xt[64][DHEAD + 1];
  __shared__ float acs_s[CHUNKC];

  acs_s[tid] = Acs[((size_t)bid << 8) + tid];
  __syncthreads();
  const float A_last = acs_s[CHUNKC - 1];

  const int n0 = (tid >> 3) * 4;
  const int d0 = (tid & 7) * 8;
  float acc[4][8];
#pragma unroll
  for (int i = 0; i < 4; ++i)
#pragma unroll
    for (int j = 0; j < 8; ++j) acc[i][j] = 0.f;

  const size_t rowbase = (size_t)(b * SEQ + c * CHUNKC) * CONV_DIMC;
  for (int t0 = 0; t0 < CHUNKC; t0 += 64) {
#pragma unroll
    for (int i = 0; i < 32; ++i) {
      const int idx = tid + i * 256;
      const int r = idx >> 7, col = idx & 127;
      Bt[r][col] = bf2f(convout[rowbase + (size_t)(t0 + r) * CONV_DIMC + D_INNERC + g * NST + col]);
    }
#pragma unroll
    for (int i = 0; i < 16; ++i) {
      const int idx = tid + i * 256;
      const int r = idx >> 6, d = idx & 63;
      Xt[r][d] = bf2f(convout[rowbase + (size_t)(t0 + r) * CONV_DIMC + h * DHEAD + d]) *
                 expf(A_last - acs_s[t0 + r]);
    }
    __syncthreads();
    for (int tt = 0; tt < 64; ++tt) {
      float bv[4], xv[8];
#pragma unroll
      for (int i = 0; i < 4; ++i) bv[i] = Bt[tt][n0 + i];
#pragma unroll
      for (int j = 0; j < 8; ++j) xv[j] = Xt[tt][d0 + j];
#pragma unroll
      for (int i = 0; i < 4; ++i)
#pragma unroll
        for (int j = 0; j < 8; ++j) acc[i][j] += bv[i] * xv[j];
    }
    __syncthreads();
  }
  float* sp = states + ((size_t)bid << 13);
#pragma unroll
  for (int i = 0; i < 4; ++i)
#pragma unroll
    for (int j = 0; j < 8; ++j) sp[(n0 + i) * DHEAD + d0 + j] = acc[i][j];
}

// ---------------- 8. sequential chunk scan (fp32, h_prev in place) ----------------
__global__ __launch_bounds__(256) void chunkscan_kernel(
    float* __restrict__ states_hprev, const float* __restrict__ Acs,
    float* __restrict__ hfinal) {
  const size_t i = (size_t)blockIdx.x * 256 + threadIdx.x;
  const int b = (int)(i >> 19);
  const int h = (int)((i >> 13) & 63);
  const int nd = (int)(i & 8191);
  float hv = 0.f;
#pragma unroll
  for (int c = 0; c < NCHUNK; ++c) {
    const int bch = (b * NCHUNK + c) * NH + h;
    const size_t sidx = ((size_t)bch << 13) + nd;
    const float st = states_hprev[sidx];
    const float cd = expf(Acs[((size_t)bch << 8) + 255]);
    states_hprev[sidx] = hv;
    hv = hv * cd + st;
  }
  hfinal[((size_t)(b * NH + h) << 13) + nd] = hv;
}

// ---------------- 9. Y = diag + carry (bf16 out, [4096][4096]) ----------------
__global__ __launch_bounds__(256) void y_kernel(
    const unsigned short* __restrict__ convout, const float* __restrict__ Acs,
    const unsigned short* __restrict__ CB, const float* __restrict__ hprev,
    unsigned short* __restrict__ Ybuf) {
  const int bid = blockIdx.x;
  const int h = bid & 63;
  const int c = (bid >> 6) & 7;
  const int b = bid >> 9;
  const int g = h >> 3;
  const int t = threadIdx.x;

  __shared__ float hs[NST][DHEAD];
  __shared__ float xs[64][DHEAD];
  __shared__ float acs_s[CHUNKC];

  acs_s[t] = Acs[((size_t)bid << 8) + t];
  {
    const float* hp = hprev + ((size_t)bid << 13);
#pragma unroll
    for (int i = 0; i < 32; ++i) {
      const int idx = t + i * 256;
      ((float*)hs)[idx] = hp[idx];
    }
  }
  __syncthreads();

  float4 acc[16];
#pragma unroll
  for (int i = 0; i < 16; ++i) acc[i] = make_float4(0.f, 0.f, 0.f, 0.f);

  const size_t rowbase = (size_t)(b * SEQ + c * CHUNKC) * CONV_DIMC;
  const unsigned short* c16 = convout + rowbase + (size_t)t * CONV_DIMC + D_INNERC + GNC + g * NST;
  for (int n4 = 0; n4 < 32; ++n4) {
    const uint2 cq = *(const uint2*)(c16 + n4 * 4);
    const float cv_[4] = {bf2f((unsigned short)(cq.x & 0xffff)), bf2f((unsigned short)(cq.x >> 16)),
                          bf2f((unsigned short)(cq.y & 0xffff)), bf2f((unsigned short)(cq.y >> 16))};
#pragma unroll
    for (int l = 0; l < 4; ++l) {
      const float cv = cv_[l];
      const float4* hr = (const float4*)hs[n4 * 4 + l];
#pragma unroll
      for (int j = 0; j < 16; ++j) {
        const float4 hv = hr[j];
        acc[j].x += cv * hv.x; acc[j].y += cv * hv.y;
        acc[j].z += cv * hv.z; acc[j].w += cv * hv.w;
      }
    }
  }
  const float at = acs_s[t];
  const float ea = expf(at);
#pragma unroll
  for (int j = 0; j < 16; ++j) {
    acc[j].x *= ea; acc[j].y *= ea; acc[j].z *= ea; acc[j].w *= ea;
  }
  const unsigned short* cbrow = CB + ((size_t)((b * NCHUNK + c) * NG + g) << 16) + (size_t)t * CHUNKC;
  for (int s0 = 0; s0 < CHUNKC; s0 += 64) {
    __syncthreads();
#pragma unroll
    for (int i = 0; i < 16; ++i) {
      const int idx = t + i * 256;
      const int r = idx >> 6, d = idx & 63;
      xs[r][d] = bf2f(convout[rowbase + (size_t)(s0 + r) * CONV_DIMC + h * DHEAD + d]);
    }
    __syncthreads();
    if (s0 <= t) {
      const int smax = min(64, t - s0 + 1);
      for (int ssi = 0; ssi < smax; ++ssi) {
        const float w = expf(at - acs_s[s0 + ssi]) * bf2f(cbrow[s0 + ssi]);
        const float4* xr = (const float4*)xs[ssi];
#pragma unroll
        for (int j = 0; j < 16; ++j) {
          const float4 xv = xr[j];
          acc[j].x += w * xv.x; acc[j].y += w * xv.y;
          acc[j].z += w * xv.z; acc[j].w += w * xv.w;
        }
      }
    }
  }
  unsigned* yp = (unsigned*)(Ybuf + (size_t)(b * SEQ + c * CHUNKC + t) * D_INNERC + h * DHEAD);
#pragma unroll
  for (int j = 0; j < 16; ++j) {
    yp[2 * j]     = (unsigned)f2bf(acc[j].x) | ((unsigned)f2bf(acc[j].y) << 16);
    yp[2 * j + 1] = (unsigned)f2bf(acc[j].z) | ((unsigned)f2bf(acc[j].w) << 16);
  }
}

// ---------------- 10. out-norm * silu(gate), in place on Y bf16 ----------------
__global__ __launch_bounds__(256) void ynorm_kernel(
    unsigned short* __restrict__ Ybuf, const unsigned short* __restrict__ gate,
    const float* __restrict__ onw) {
  const int row = blockIdx.x;
  const int tid = threadIdx.x;
  unsigned short* yrow = Ybuf + (size_t)row * D_INNERC;
  const unsigned short* grow = gate + (size_t)row * D_INNERC;
  float v[16];
  float ss = 0.f;
#pragma unroll
  for (int i = 0; i < 2; ++i) {
    const int g8 = tid + i * 256;
    const uint4 q = ((const uint4*)yrow)[g8];
    const unsigned qq[4] = {q.x, q.y, q.z, q.w};
#pragma unroll
    for (int j = 0; j < 4; ++j) {
      const float a = bf2f((unsigned short)(qq[j] & 0xffff));
      const float bb = bf2f((unsigned short)(qq[j] >> 16));
      v[i * 8 + 2 * j] = a;
      v[i * 8 + 2 * j + 1] = bb;
      ss += a * a + bb * bb;
    }
  }
  ss = block_sum256(ss);
  const float rms = rsqrtf(ss * (1.0f / D_INNERC) + 1e-6f);
#pragma unroll
  for (int i = 0; i < 2; ++i) {
    const int g8 = tid + i * 256;
    const uint4 gq = ((const uint4*)grow)[g8];
    const unsigned gg[4] = {gq.x, gq.y, gq.z, gq.w};
    const float4 w0 = ((const float4*)onw)[g8 * 2];
    const float4 w1 = ((const float4*)onw)[g8 * 2 + 1];
    const float w_[8] = {w0.x, w0.y, w0.z, w0.w, w1.x, w1.y, w1.z, w1.w};
    uint4 o;
    unsigned oo[4];
#pragma unroll
    for (int j = 0; j < 4; ++j) {
      const float ga = siluf(bf2f((unsigned short)(gg[j] & 0xffff)));
      const float gb = siluf(bf2f((unsigned short)(gg[j] >> 16)));
      const float ya = v[i * 8 + 2 * j] * rms * w_[2 * j] * ga;
      const float yb = v[i * 8 + 2 * j + 1] * rms * w_[2 * j + 1] * gb;
      oo[j] = (unsigned)f2bf(ya) | ((unsigned)f2bf(yb) << 16);
    }
    o.x = oo[0]; o.y = oo[1]; o.z = oo[2]; o.w = oo[3];
    ((uint4*)yrow)[g8] = o;
  }
}

extern "C" void kernel_launch(void* const* d_in, const int* in_sizes, int n_in,
                              void* d_out, int out_size, void* d_ws, size_t ws_size,
                              hipStream_t stream) {
  const float* x           = (const float*)d_in[0];
  const float* norm_w      = (const float*)d_in[1];
  const float* in_proj_w   = (const float*)d_in[2];
  const float* conv_w      = (const float*)d_in[3];
  const float* conv_b      = (const float*)d_in[4];
  const float* conv_norm_w = (const float*)d_in[5];
  const float* A_log       = (const float*)d_in[6];
  const float* dt_w        = (const float*)d_in[7];
  const float* dt_b        = (const float*)d_in[8];
  const float* out_norm_w  = (const float*)d_in[9];
  const float* out_proj_w  = (const float*)d_in[10];
  float* out = (float*)d_out;
  char* base = (char*)d_ws;

  // ws layout (bytes), total 204,472,320 (unchanged):
  //   [0,            50331648)  convin bf16 [4096][6144]; later aliased: Y bf16 [4096][4096]
  //   [50331648,    100663296)  convout bf16 [4096][6144]
  //                             ALIASED EARLY: W1hi bf16 [10368][2048] (dead before conv_norm)
  //                             ALIASED LATE:  W2hi bf16 [2048][4096]  (after y_kernel)
  //   [100663296,   134217728)  gate bf16 [4096][4096]
  //   [134217728,   150994944)  xn_hi bf16 [4096][2048]; later aliased: CB bf16
  //   [150994944,   167772160)  xn_lo bf16 [4096][2048]
  //   [167772160,   201326592)  states fp32 (h_prev in place)
  //   [201326592,   202375168)  A_dt fp32 [4096][64]
  //   [202375168,   203423744)  Aarr fp32
  //   [203423744,   204472320)  Acs fp32
  unsigned short* convin  = (unsigned short*)(base);
  unsigned short* Ybuf    = (unsigned short*)(base);
  unsigned short* convout = (unsigned short*)(base + 50331648ull);
  unsigned short* W1hi    = (unsigned short*)(base + 50331648ull);  // alias, pre-conv_norm
  unsigned short* W2hi    = (unsigned short*)(base + 50331648ull);  // alias, post-y_kernel
  unsigned short* gate    = (unsigned short*)(base + 100663296ull);
  unsigned short* xnhi    = (unsigned short*)(base + 134217728ull);
  unsigned short* CBbuf   = (unsigned short*)(base + 134217728ull); // alias (xn dead)
  unsigned short* xnlo    = (unsigned short*)(base + 150994944ull);
  float*          states  = (float*)(base + 167772160ull);
  float*          A_dt    = (float*)(base + 201326592ull);
  float*          Aarr    = (float*)(base + 202375168ull);
  float*          Acs     = (float*)(base + 203423744ull);

  if (ws_size < 204472320ull) return;  // fail-clean signature: Output0 err == 5.9375

  float* hfinal = out + 8388608ull;

  rmsnorm_in_kernel<<<ROWS, 256, 0, stream>>>(x, norm_w, xnhi, xnlo);
  // W1 -> bf16 plane (padded to 10368 rows with zeros)
  wconv_kernel<<<(10368 * 2048 / 8 + 255) / 256, 256, 0, stream>>>(
      in_proj_w, W1hi, IN_PROJC * D_MODELC, 10368 * 2048);
  // GEMM1 fast: pure bf16 + global_load_lds; skips the A_dt block (y==32)
  mfma_gemm_fast<0><<<dim3(ROWS / 128, 81), 256, 0, stream>>>(
      xnhi, D_MODELC, W1hi, D_MODELC, 32,
      convin, A_dt, gate, nullptr, nullptr, 0);
  // GEMM1 split: the accuracy-critical A_dt block only (n0=4096..4223)
  mfma_gemm_split<<<dim3(ROWS / 128, 1), 256, 0, stream>>>(
      xnhi, xnlo, D_MODELC, in_proj_w, IN_PROJC, D_MODELC, 32,
      convin, A_dt, gate);
  conv_norm_kernel<<<ROWS, 256, 0, stream>>>(convin, conv_w, conv_b, conv_norm_w, convout);
  dt_kernel<<<ROWS, 64, 0, stream>>>(A_dt, dt_w, dt_b, A_log, Aarr);
  cumsum_kernel<<<BATCH * NCHUNK * NH, 256, 0, stream>>>(Aarr, Acs);
  cb_kernel<<<BATCH * NCHUNK * NG * 4, 256, 0, stream>>>(convout, CBbuf);
  states_kernel<<<BATCH * NCHUNK * NH, 256, 0, stream>>>(convout, Acs, states);
  chunkscan_kernel<<<4096, 256, 0, stream>>>(states, Acs, hfinal);
  y_kernel<<<BATCH * NCHUNK * NH, 256, 0, stream>>>(convout, Acs, CBbuf, states, Ybuf);
  // W2 -> bf16 plane (convout region now dead)
  wconv_kernel<<<(2048 * 4096 / 8 + 255) / 256, 256, 0, stream>>>(
      out_proj_w, W2hi, D_MODELC * D_INNERC, 2048 * 4096);
  ynorm_kernel<<<ROWS, 256, 0, stream>>>(Ybuf, gate, out_norm_w);
  // GEMM2 fast: Ybuf bf16 x W2hi bf16 + residual
  mfma_gemm_fast<1><<<dim3(ROWS / 128, D_MODELC / 128), 256, 0, stream>>>(
      Ybuf, D_INNERC, W2hi, D_INNERC, -1,
      nullptr, nullptr, nullptr, out, x, D_MODELC);
}

// Round 9
// 1040.714 us; speedup vs baseline: 1.9127x; 1.4414x over previous
//
#include <hip/hip_runtime.h>
#include <math.h>

// ---- problem constants ----
#define D_MODELC 2048
#define D_INNERC 4096
#define NH 64        // H heads
#define DHEAD 64     // D_HEAD
#define NST 128      // N state dim
#define NG 8         // G groups
#define CHUNKC 256
#define GNC 1024     // G*N
#define CONV_DIMC 6144
#define IN_PROJC 10304
#define BATCH 2
#define SEQ 2048
#define NCHUNK 8
#define ROWS 4096
// proj column map: [X 0:4096 | A_dt 4096:4160 | B 4160:5184 | C 5184:6208 | gate 6208:10304]

typedef __attribute__((ext_vector_type(8))) short bf16x8;
typedef __attribute__((ext_vector_type(4))) float f32x4;

__device__ __forceinline__ float bf2f(unsigned short h) {
  return __uint_as_float(((unsigned)h) << 16);
}
__device__ __forceinline__ unsigned short f2bf(float f) {
  unsigned u = __float_as_uint(f);
  u += 0x7FFFu + ((u >> 16) & 1u);   // round-to-nearest-even
  return (unsigned short)(u >> 16);
}
__device__ __forceinline__ unsigned cvtpk(float a, float b) {
  unsigned r;
  asm("v_cvt_pk_bf16_f32 %0, %1, %2" : "=v"(r) : "v"(a), "v"(b));
  return r;
}
__device__ __forceinline__ uint4 pack8_cvt(const float* f) {
  uint4 r;
  r.x = cvtpk(f[0], f[1]); r.y = cvtpk(f[2], f[3]);
  r.z = cvtpk(f[4], f[5]); r.w = cvtpk(f[6], f[7]);
  return r;
}
__device__ __forceinline__ void resid8(const float* f, uint4 q, float* lo) {
  lo[0] = f[0] - __uint_as_float(q.x << 16);
  lo[1] = f[1] - __uint_as_float(q.x & 0xffff0000u);
  lo[2] = f[2] - __uint_as_float(q.y << 16);
  lo[3] = f[3] - __uint_as_float(q.y & 0xffff0000u);
  lo[4] = f[4] - __uint_as_float(q.z << 16);
  lo[5] = f[5] - __uint_as_float(q.z & 0xffff0000u);
  lo[6] = f[6] - __uint_as_float(q.w << 16);
  lo[7] = f[7] - __uint_as_float(q.w & 0xffff0000u);
}
__device__ __forceinline__ float siluf(float x) { return x / (1.0f + expf(-x)); }

// async global->LDS, 16 bytes per lane; LDS dest is wave-uniform base + lane*16
__device__ __forceinline__ void gload16(const unsigned short* g, unsigned short* l) {
  __builtin_amdgcn_global_load_lds(
      (const __attribute__((address_space(1))) void*)g,
      (__attribute__((address_space(3))) void*)l, 16, 0, 0);
}

__device__ __forceinline__ float block_sum256(float v) {
#pragma unroll
  for (int off = 32; off > 0; off >>= 1) v += __shfl_down(v, off, 64);
  __shared__ float red[4];
  const int lane = threadIdx.x & 63, wv = threadIdx.x >> 6;
  if (lane == 0) red[wv] = v;
  __syncthreads();
  float s = red[0] + red[1] + red[2] + red[3];
  __syncthreads();
  return s;
}

// ---------------- 0. W fp32 -> bf16(hi) plane ----------------
__global__ __launch_bounds__(256) void wconv_kernel(
    const float* __restrict__ W, unsigned short* __restrict__ Whi,
    int n_valid, int n_total) {
  const int i = (blockIdx.x * 256 + threadIdx.x) * 8;
  if (i >= n_total) return;
  float v[8];
  if (i + 8 <= n_valid) {
    *(float4*)&v[0] = *(const float4*)(W + i);
    *(float4*)&v[4] = *(const float4*)(W + i + 4);
  } else {
#pragma unroll
    for (int j = 0; j < 8; ++j) v[j] = 0.f;
  }
  *(uint4*)&Whi[i] = pack8_cvt(v);
}

// ---------------- 1. input rmsnorm -> bf16 hi/lo planes ----------------
__global__ __launch_bounds__(256) void rmsnorm_in_kernel(
    const float* __restrict__ x, const float* __restrict__ nw,
    unsigned short* __restrict__ xnhi, unsigned short* __restrict__ xnlo) {
  const int row = blockIdx.x;
  const int tid = threadIdx.x;
  const float4* xr = (const float4*)(x + (size_t)row * D_MODELC);
  float4 v[2];
  float ss = 0.f;
#pragma unroll
  for (int i = 0; i < 2; ++i) {
    v[i] = xr[tid + i * 256];
    ss += v[i].x * v[i].x + v[i].y * v[i].y + v[i].z * v[i].z + v[i].w * v[i].w;
  }
  ss = block_sum256(ss);
  const float rms = rsqrtf(ss * (1.0f / D_MODELC) + 1e-6f);
  const float4* wp = (const float4*)nw;
#pragma unroll
  for (int i = 0; i < 2; ++i) {
    const int idx = tid + i * 256;
    const float4 w4 = wp[idx];
    float a = v[i].x * rms * w4.x;
    float b = v[i].y * rms * w4.y;
    float c = v[i].z * rms * w4.z;
    float d = v[i].w * rms * w4.w;
    unsigned h0 = cvtpk(a, b), h1 = cvtpk(c, d);
    float la = a - __uint_as_float(h0 << 16);
    float lb = b - __uint_as_float(h0 & 0xffff0000u);
    float lc = c - __uint_as_float(h1 << 16);
    float ld = d - __uint_as_float(h1 & 0xffff0000u);
    unsigned l0 = cvtpk(la, lb), l1 = cvtpk(lc, ld);
    *(uint2*)&xnhi[(size_t)row * D_MODELC + idx * 4] = make_uint2(h0, h1);
    *(uint2*)&xnlo[(size_t)row * D_MODELC + idx * 4] = make_uint2(l0, l1);
  }
}

// ---------------- 2a. FAST MFMA GEMM (pure bf16, global_load_lds staging) ----------------
template <int EPI>
__global__ __launch_bounds__(256) void mfma_gemm_fast(
    const unsigned short* __restrict__ Ahi, int lda,
    const unsigned short* __restrict__ Wq, int K, int skipy,
    unsigned short* __restrict__ convin, float* __restrict__ A_dt,
    unsigned short* __restrict__ gate,
    float* __restrict__ Cout, const float* __restrict__ res, int ldc) {
  __shared__ __align__(16) unsigned short As[128 * 32];
  __shared__ __align__(16) unsigned short Ws[128 * 32];
  if (EPI == 0 && (int)blockIdx.y == skipy) return;

  const int tid = threadIdx.x;
  const int m0 = blockIdx.x * 128;
  const int n0 = blockIdx.y * 128;
  const int lane = tid & 63, wv = tid >> 6;
  const int wr = (wv >> 1) * 64, wc = (wv & 1) * 64;
  const int fr = lane & 15, kb = lane >> 4;

  const int arow = tid >> 2, acol = (tid & 3) * 8;
  const unsigned short* ga0 = Ahi + (size_t)(m0 + arow) * lda + acol;
  const unsigned short* ga1 = ga0 + (size_t)64 * lda;
  const unsigned short* gw0 = Wq + (size_t)(n0 + arow) * K + acol;
  const unsigned short* gw1 = gw0 + (size_t)64 * K;
  unsigned short* la0 = &As[(tid >> 6) * 512];
  unsigned short* la1 = &As[2048 + (tid >> 6) * 512];
  unsigned short* lw0 = &Ws[(tid >> 6) * 512];
  unsigned short* lw1 = &Ws[2048 + (tid >> 6) * 512];

  f32x4 acc[4][4];
#pragma unroll
  for (int i = 0; i < 4; ++i)
#pragma unroll
    for (int j = 0; j < 4; ++j) acc[i][j] = (f32x4){0.f, 0.f, 0.f, 0.f};

  for (int k0 = 0; k0 < K; k0 += 32) {
    __syncthreads();
    gload16(ga0 + k0, la0);
    gload16(ga1 + k0, la1);
    gload16(gw0 + k0, lw0);
    gload16(gw1 + k0, lw1);
    __syncthreads();

    bf16x8 ah[4], bh[4];
#pragma unroll
    for (int mi = 0; mi < 4; ++mi)
      ah[mi] = *(const bf16x8*)&As[(wr + mi * 16 + fr) * 32 + kb * 8];
#pragma unroll
    for (int ni = 0; ni < 4; ++ni)
      bh[ni] = *(const bf16x8*)&Ws[(wc + ni * 16 + fr) * 32 + kb * 8];
#pragma unroll
    for (int mi = 0; mi < 4; ++mi)
#pragma unroll
      for (int ni = 0; ni < 4; ++ni)
        acc[mi][ni] = __builtin_amdgcn_mfma_f32_16x16x32_bf16(ah[mi], bh[ni], acc[mi][ni], 0, 0, 0);
  }

#pragma unroll
  for (int mi = 0; mi < 4; ++mi)
#pragma unroll
    for (int ni = 0; ni < 4; ++ni) {
      const int gn = n0 + wc + ni * 16 + fr;
#pragma unroll
      for (int r = 0; r < 4; ++r) {
        const int gm = m0 + wr + mi * 16 + kb * 4 + r;
        const float v = acc[mi][ni][r];
        if (EPI == 0) {
          if (gn < D_INNERC) {
            convin[(size_t)gm * CONV_DIMC + gn] = f2bf(v);
          } else if (gn < D_INNERC + NH) {
            A_dt[(size_t)gm * NH + (gn - D_INNERC)] = v;
          } else if (gn < D_INNERC + NH + 2 * GNC) {
            convin[(size_t)gm * CONV_DIMC + (gn - NH)] = f2bf(v);
          } else if (gn < IN_PROJC) {
            gate[(size_t)gm * D_INNERC + (gn - D_INNERC - NH - 2 * GNC)] = f2bf(v);
          }
        } else {
          Cout[(size_t)gm * ldc + gn] = v + res[(size_t)gm * ldc + gn];
        }
      }
    }
}

// ---------------- 2b. SPLIT MFMA GEMM (register staging, hi/lo, 3 MFMA) ----------------
__global__ __launch_bounds__(256) void mfma_gemm_split(
    const unsigned short* __restrict__ Ahi, const unsigned short* __restrict__ Alo, int lda,
    const float* __restrict__ W, int N, int K, int ybase,
    unsigned short* __restrict__ convin, float* __restrict__ A_dt,
    unsigned short* __restrict__ gate) {
  __shared__ unsigned short As_hi[128 * 32];
  __shared__ unsigned short Bs_hi[128 * 32];
  __shared__ unsigned short As_lo[128 * 32];
  __shared__ unsigned short Bs_lo[128 * 32];

  const int tid = threadIdx.x;
  const int m0 = blockIdx.x * 128;
  const int n0 = (blockIdx.y + ybase) * 128;
  const int lane = tid & 63, wv = tid >> 6;
  const int wr = (wv >> 1) * 64, wc = (wv & 1) * 64;
  const int fr = lane & 15, kb = lane >> 4;
  const int srow = tid >> 1;
  const int shalf = tid & 1;

  f32x4 acc[4][4];
#pragma unroll
  for (int i = 0; i < 4; ++i)
#pragma unroll
    for (int j = 0; j < 4; ++j) acc[i][j] = (f32x4){0.f, 0.f, 0.f, 0.f};

  const int c0s = (shalf * 2) ^ (srow & 3);
  const int c1s = (shalf * 2 + 1) ^ (srow & 3);
  const int wbase = srow * 32;

  for (int k0 = 0; k0 < K; k0 += 32) {
    __syncthreads();
    {
      const unsigned short* sh = Ahi + (size_t)(m0 + srow) * lda + k0 + shalf * 16;
      *(uint4*)&As_hi[wbase + c0s * 8] = *(const uint4*)(sh);
      *(uint4*)&As_hi[wbase + c1s * 8] = *(const uint4*)(sh + 8);
      const unsigned short* sl = Alo + (size_t)(m0 + srow) * lda + k0 + shalf * 16;
      *(uint4*)&As_lo[wbase + c0s * 8] = *(const uint4*)(sl);
      *(uint4*)&As_lo[wbase + c1s * 8] = *(const uint4*)(sl + 8);
    }
    {
      const int gn = n0 + srow;
      float v[16];
      const float* src = W + (size_t)gn * K + k0 + shalf * 16;
      *(float4*)&v[0] = *(const float4*)(src);
      *(float4*)&v[4] = *(const float4*)(src + 4);
      *(float4*)&v[8] = *(const float4*)(src + 8);
      *(float4*)&v[12] = *(const float4*)(src + 12);
      uint4 qh0 = pack8_cvt(&v[0]);
      uint4 qh1 = pack8_cvt(&v[8]);
      *(uint4*)&Bs_hi[wbase + c0s * 8] = qh0;
      *(uint4*)&Bs_hi[wbase + c1s * 8] = qh1;
      float lo[16];
      resid8(&v[0], qh0, &lo[0]);
      resid8(&v[8], qh1, &lo[8]);
      *(uint4*)&Bs_lo[wbase + c0s * 8] = pack8_cvt(&lo[0]);
      *(uint4*)&Bs_lo[wbase + c1s * 8] = pack8_cvt(&lo[8]);
    }
    __syncthreads();

    bf16x8 ah[4], bh[4], al[4], bl[4];
#pragma unroll
    for (int mi = 0; mi < 4; ++mi) {
      const int row = wr + mi * 16 + fr;
      const int off = row * 32 + ((kb ^ (row & 3)) * 8);
      ah[mi] = *(const bf16x8*)&As_hi[off];
      al[mi] = *(const bf16x8*)&As_lo[off];
    }
#pragma unroll
    for (int ni = 0; ni < 4; ++ni) {
      const int row = wc + ni * 16 + fr;
      const int off = row * 32 + ((kb ^ (row & 3)) * 8);
      bh[ni] = *(const bf16x8*)&Bs_hi[off];
      bl[ni] = *(const bf16x8*)&Bs_lo[off];
    }
#pragma unroll
    for (int mi = 0; mi < 4; ++mi)
#pragma unroll
      for (int ni = 0; ni < 4; ++ni) {
        acc[mi][ni] = __builtin_amdgcn_mfma_f32_16x16x32_bf16(ah[mi], bh[ni], acc[mi][ni], 0, 0, 0);
        acc[mi][ni] = __builtin_amdgcn_mfma_f32_16x16x32_bf16(ah[mi], bl[ni], acc[mi][ni], 0, 0, 0);
        acc[mi][ni] = __builtin_amdgcn_mfma_f32_16x16x32_bf16(al[mi], bh[ni], acc[mi][ni], 0, 0, 0);
      }
  }

#pragma unroll
  for (int mi = 0; mi < 4; ++mi)
#pragma unroll
    for (int ni = 0; ni < 4; ++ni) {
      const int gn = n0 + wc + ni * 16 + fr;
#pragma unroll
      for (int r = 0; r < 4; ++r) {
        const int gm = m0 + wr + mi * 16 + kb * 4 + r;
        const float v = acc[mi][ni][r];
        if (gn < D_INNERC) {
          convin[(size_t)gm * CONV_DIMC + gn] = f2bf(v);
        } else if (gn < D_INNERC + NH) {
          A_dt[(size_t)gm * NH + (gn - D_INNERC)] = v;
        } else if (gn < D_INNERC + NH + 2 * GNC) {
          convin[(size_t)gm * CONV_DIMC + (gn - NH)] = f2bf(v);
        } else if (gn < IN_PROJC) {
          gate[(size_t)gm * D_INNERC + (gn - D_INNERC - NH - 2 * GNC)] = f2bf(v);
        }
      }
    }
}

// ---------------- 3. depthwise conv(4, causal) + rmsnorm + silu (bf16 io) ----------------
__global__ __launch_bounds__(256) void conv_norm_kernel(
    const unsigned short* __restrict__ convin, const float* __restrict__ conv_w,
    const float* __restrict__ conv_b, const float* __restrict__ cnw,
    unsigned short* __restrict__ convout) {
  const int row = blockIdx.x;
  const int t = row & (SEQ - 1);
  const int tid = threadIdx.x;
  float vals[24];
  float ss = 0.f;
#pragma unroll
  for (int i = 0; i < 24; ++i) {
    const int c = tid + i * 256;
    float acc = conv_b[c];
    const float4 w4 = *(const float4*)(conv_w + c * 4);
    const float w_[4] = {w4.x, w4.y, w4.z, w4.w};
#pragma unroll
    for (int k = 0; k < 4; ++k) {
      const int tt = t - 3 + k;
      if (tt >= 0) acc += w_[k] * bf2f(convin[(size_t)(row - 3 + k) * CONV_DIMC + c]);
    }
    vals[i] = acc;
    ss += acc * acc;
  }
  ss = block_sum256(ss);
  const float rms = rsqrtf(ss * (1.0f / CONV_DIMC) + 1e-6f);
#pragma unroll
  for (int i = 0; i < 24; ++i) {
    const int c = tid + i * 256;
    convout[(size_t)row * CONV_DIMC + c] = f2bf(siluf(vals[i] * rms * cnw[c]));
  }
}

// ---------------- 4. dt/A ----------------
__global__ __launch_bounds__(64) void dt_kernel(
    const float* __restrict__ A_dt_buf, const float* __restrict__ dt_w,
    const float* __restrict__ dt_b, const float* __restrict__ A_log,
    float* __restrict__ Aarr) {
  const int row = blockIdx.x;
  const int h = threadIdx.x;
  __shared__ float ad[NH];
  ad[h] = A_dt_buf[(size_t)row * NH + h];
  __syncthreads();
  float s = dt_b[h];
  const float* wr = dt_w + h * NH;
#pragma unroll 8
  for (int j = 0; j < NH; ++j) s += ad[j] * wr[j];
  const float dt = (s > 20.f) ? s : log1pf(expf(s));
  const float a = -expf(A_log[h]) * dt;
  const int b = row >> 11;
  const int t = row & (SEQ - 1);
  const int c = t >> 8, tt = t & 255;
  Aarr[(((size_t)(b * NCHUNK + c) * NH + h) << 8) + tt] = a;  // [b][c][h][t]
}

// ---------------- 5. per-chunk inclusive cumsum ----------------
__global__ __launch_bounds__(256) void cumsum_kernel(
    const float* __restrict__ Aarr, float* __restrict__ Acs) {
  const size_t base = (size_t)blockIdx.x << 8;
  const int tid = threadIdx.x;
  __shared__ float s[CHUNKC];
  s[tid] = Aarr[base + tid];
  __syncthreads();
  for (int off = 1; off < CHUNKC; off <<= 1) {
    const float xv = (tid >= off) ? s[tid - off] : 0.f;
    __syncthreads();
    s[tid] += xv;
    __syncthreads();
  }
  Acs[base + tid] = s[tid];
}

// ---------------- 6. CB gram via MFMA: CB[t][s] = sum_n C[t,n]*B[s,n] ----------------
// grid 512: quad = bid&3 (t-half, s-half), g, c, b. 128x128 tile, K=128.
__global__ __launch_bounds__(256) void cb_mfma_kernel(
    const unsigned short* __restrict__ convout, unsigned short* __restrict__ CB) {
  __shared__ __align__(16) unsigned short As[128 * 32];
  __shared__ __align__(16) unsigned short Bs[128 * 32];
  const int bid = blockIdx.x;
  const int quad = bid & 3;
  const int g = (bid >> 2) & 7;
  const int c = (bid >> 5) & 7;
  const int b = bid >> 8;
  const int t0 = (quad >> 1) * 128;
  const int s0 = (quad & 1) * 128;
  const int tid = threadIdx.x;
  const int lane = tid & 63;
  const int wv = tid >> 6;
  const int wr = (wv >> 1) * 64, wc = (wv & 1) * 64;
  const int fr = lane & 15, kb = lane >> 4;

  const size_t rowbase = (size_t)(b * SEQ + c * CHUNKC) * CONV_DIMC;
  const int arow = tid >> 2, acol = (tid & 3) * 8;
  const unsigned short* ga0 = convout + rowbase + (size_t)(t0 + arow) * CONV_DIMC + D_INNERC + GNC + g * NST + acol;
  const unsigned short* ga1 = ga0 + (size_t)64 * CONV_DIMC;
  const unsigned short* gb0 = convout + rowbase + (size_t)(s0 + arow) * CONV_DIMC + D_INNERC + g * NST + acol;
  const unsigned short* gb1 = gb0 + (size_t)64 * CONV_DIMC;
  unsigned short* la0 = &As[(tid >> 6) * 512];
  unsigned short* la1 = &As[2048 + (tid >> 6) * 512];
  unsigned short* lb0 = &Bs[(tid >> 6) * 512];
  unsigned short* lb1 = &Bs[2048 + (tid >> 6) * 512];

  f32x4 acc[4][4];
#pragma unroll
  for (int i = 0; i < 4; ++i)
#pragma unroll
    for (int j = 0; j < 4; ++j) acc[i][j] = (f32x4){0.f, 0.f, 0.f, 0.f};

  for (int k0 = 0; k0 < NST; k0 += 32) {
    __syncthreads();
    gload16(ga0 + k0, la0);
    gload16(ga1 + k0, la1);
    gload16(gb0 + k0, lb0);
    gload16(gb1 + k0, lb1);
    __syncthreads();
    bf16x8 ah[4], bh[4];
#pragma unroll
    for (int mi = 0; mi < 4; ++mi)
      ah[mi] = *(const bf16x8*)&As[(wr + mi * 16 + fr) * 32 + kb * 8];
#pragma unroll
    for (int ni = 0; ni < 4; ++ni)
      bh[ni] = *(const bf16x8*)&Bs[(wc + ni * 16 + fr) * 32 + kb * 8];
#pragma unroll
    for (int mi = 0; mi < 4; ++mi)
#pragma unroll
      for (int ni = 0; ni < 4; ++ni)
        acc[mi][ni] = __builtin_amdgcn_mfma_f32_16x16x32_bf16(ah[mi], bh[ni], acc[mi][ni], 0, 0, 0);
  }

  unsigned short* cbp = CB + ((size_t)((b * NCHUNK + c) * NG + g) << 16);
#pragma unroll
  for (int mi = 0; mi < 4; ++mi)
#pragma unroll
    for (int ni = 0; ni < 4; ++ni) {
      const int scol = s0 + wc + ni * 16 + fr;
#pragma unroll
      for (int r = 0; r < 4; ++r) {
        const int trow = t0 + wr + mi * 16 + kb * 4 + r;
        cbp[(size_t)trow * CHUNKC + scol] = f2bf(acc[mi][ni][r]);
      }
    }
}

// ---------------- 7. chunk states (bf16 in, fp32 out) ----------------
__global__ __launch_bounds__(256) void states_kernel(
    const unsigned short* __restrict__ convout, const float* __restrict__ Acs,
    float* __restrict__ states) {
  const int bid = blockIdx.x;
  const int h = bid & 63;
  const int c = (bid >> 6) & 7;
  const int b = bid >> 9;
  const int g = h >> 3;
  const int tid = threadIdx.x;

  __shared__ float Bt[64][NST];
  __shared__ float Xt[64][DHEAD + 1];
  __shared__ float acs_s[CHUNKC];

  acs_s[tid] = Acs[((size_t)bid << 8) + tid];
  __syncthreads();
  const float A_last = acs_s[CHUNKC - 1];

  const int n0 = (tid >> 3) * 4;
  const int d0 = (tid & 7) * 8;
  float acc[4][8];
#pragma unroll
  for (int i = 0; i < 4; ++i)
#pragma unroll
    for (int j = 0; j < 8; ++j) acc[i][j] = 0.f;

  const size_t rowbase = (size_t)(b * SEQ + c * CHUNKC) * CONV_DIMC;
  for (int t0 = 0; t0 < CHUNKC; t0 += 64) {
#pragma unroll
    for (int i = 0; i < 32; ++i) {
      const int idx = tid + i * 256;
      const int r = idx >> 7, col = idx & 127;
      Bt[r][col] = bf2f(convout[rowbase + (size_t)(t0 + r) * CONV_DIMC + D_INNERC + g * NST + col]);
    }
#pragma unroll
    for (int i = 0; i < 16; ++i) {
      const int idx = tid + i * 256;
      const int r = idx >> 6, d = idx & 63;
      Xt[r][d] = bf2f(convout[rowbase + (size_t)(t0 + r) * CONV_DIMC + h * DHEAD + d]) *
                 expf(A_last - acs_s[t0 + r]);
    }
    __syncthreads();
    for (int tt = 0; tt < 64; ++tt) {
      float bv[4], xv[8];
#pragma unroll
      for (int i = 0; i < 4; ++i) bv[i] = Bt[tt][n0 + i];
#pragma unroll
      for (int j = 0; j < 8; ++j) xv[j] = Xt[tt][d0 + j];
#pragma unroll
      for (int i = 0; i < 4; ++i)
#pragma unroll
        for (int j = 0; j < 8; ++j) acc[i][j] += bv[i] * xv[j];
    }
    __syncthreads();
  }
  float* sp = states + ((size_t)bid << 13);
#pragma unroll
  for (int i = 0; i < 4; ++i)
#pragma unroll
    for (int j = 0; j < 8; ++j) sp[(n0 + i) * DHEAD + d0 + j] = acc[i][j];
}

// ---------------- 8. sequential chunk scan (fp32, h_prev in place) ----------------
__global__ __launch_bounds__(256) void chunkscan_kernel(
    float* __restrict__ states_hprev, const float* __restrict__ Acs,
    float* __restrict__ hfinal) {
  const size_t i = (size_t)blockIdx.x * 256 + threadIdx.x;
  const int b = (int)(i >> 19);
  const int h = (int)((i >> 13) & 63);
  const int nd = (int)(i & 8191);
  float hv = 0.f;
#pragma unroll
  for (int c = 0; c < NCHUNK; ++c) {
    const int bch = (b * NCHUNK + c) * NH + h;
    const size_t sidx = ((size_t)bch << 13) + nd;
    const float st = states_hprev[sidx];
    const float cd = expf(Acs[((size_t)bch << 8) + 255]);
    states_hprev[sidx] = hv;
    hv = hv * cd + st;
  }
  hfinal[((size_t)(b * NH + h) << 13) + nd] = hv;
}

// ---------------- 9. Y = diag + carry via MFMA ----------------
// per block (b,c,h): Y[256t][64d] = P[t,s]·X[s,d] + exp(acs_t)·(C[t,n]·hprev[n,d])
// X^T and hprev^T staged once into LDS (bf16); P built in-register from CB + exps.
__global__ __launch_bounds__(256) void y_mfma_kernel(
    const unsigned short* __restrict__ convout, const float* __restrict__ Acs,
    const unsigned short* __restrict__ CB, const float* __restrict__ hprev,
    unsigned short* __restrict__ Ybuf) {
  __shared__ float acs_s[CHUNKC];
  __shared__ unsigned short ht[64 * 136];   // [d][n], pad 136 (16B-aligned rows)
  __shared__ unsigned short xt[64 * 264];   // [d][s], pad 264

  const int bid = blockIdx.x;
  const int h = bid & 63;
  const int c = (bid >> 6) & 7;
  const int b = bid >> 9;
  const int g = h >> 3;
  const int tid = threadIdx.x;
  const int lane = tid & 63, wv = tid >> 6;
  const int fr = lane & 15, kb = lane >> 4;

  const size_t rowbase = (size_t)(b * SEQ + c * CHUNKC) * CONV_DIMC;

  acs_s[tid] = Acs[((size_t)bid << 8) + tid];

  // stage X^T: coalesced read [s][d], transposed bf16 write
#pragma unroll
  for (int p = 0; p < 8; ++p) {
    const int s = p * 32 + (tid >> 3);
    const int d0 = (tid & 7) * 8;
    uint4 q = *(const uint4*)(convout + rowbase + (size_t)s * CONV_DIMC + h * DHEAD + d0);
    const unsigned qq[4] = {q.x, q.y, q.z, q.w};
#pragma unroll
    for (int e = 0; e < 4; ++e) {
      xt[(d0 + 2 * e) * 264 + s] = (unsigned short)(qq[e] & 0xffff);
      xt[(d0 + 2 * e + 1) * 264 + s] = (unsigned short)(qq[e] >> 16);
    }
  }
  // stage hprev^T: coalesced fp32 read, bf16 transposed write
  {
    const float* hp = hprev + ((size_t)bid << 13);
#pragma unroll
    for (int p = 0; p < 8; ++p) {
      const int idx = p * 1024 + tid * 4;
      const int n = idx >> 6, d0 = idx & 63;
      float4 v = *(const float4*)(hp + idx);
      ht[(d0 + 0) * 136 + n] = f2bf(v.x);
      ht[(d0 + 1) * 136 + n] = f2bf(v.y);
      ht[(d0 + 2) * 136 + n] = f2bf(v.z);
      ht[(d0 + 3) * 136 + n] = f2bf(v.w);
    }
  }
  __syncthreads();

  f32x4 acc[4][4];
#pragma unroll
  for (int i = 0; i < 4; ++i)
#pragma unroll
    for (int j = 0; j < 4; ++j) acc[i][j] = (f32x4){0.f, 0.f, 0.f, 0.f};

  // ---- carry: K = n (128). A = C[t][n] (global), B = ht ----
  const unsigned short* crow = convout + rowbase + D_INNERC + GNC + g * NST;
#pragma unroll
  for (int k0 = 0; k0 < NST; k0 += 32) {
    bf16x8 a_[4], b_[4];
#pragma unroll
    for (int mi = 0; mi < 4; ++mi) {
      const int t = wv * 64 + mi * 16 + fr;
      a_[mi] = *(const bf16x8*)(crow + (size_t)t * CONV_DIMC + k0 + kb * 8);
    }
#pragma unroll
    for (int ni = 0; ni < 4; ++ni)
      b_[ni] = *(const bf16x8*)&ht[(ni * 16 + fr) * 136 + k0 + kb * 8];
#pragma unroll
    for (int mi = 0; mi < 4; ++mi)
#pragma unroll
      for (int ni = 0; ni < 4; ++ni)
        acc[mi][ni] = __builtin_amdgcn_mfma_f32_16x16x32_bf16(a_[mi], b_[ni], acc[mi][ni], 0, 0, 0);
  }
  // scale carry by exp(acs[t]); C/D row = (lane>>4)*4 + r
#pragma unroll
  for (int mi = 0; mi < 4; ++mi)
#pragma unroll
    for (int r = 0; r < 4; ++r) {
      const float ea = expf(acs_s[wv * 64 + mi * 16 + kb * 4 + r]);
#pragma unroll
      for (int ni = 0; ni < 4; ++ni) acc[mi][ni][r] *= ea;
    }

  // ---- diag: K = s (256, causal break). A = P (registers), B = xt ----
  const unsigned short* cbbase = CB + ((size_t)((b * NCHUNK + c) * NG + g) << 16);
  float at_[4];
#pragma unroll
  for (int mi = 0; mi < 4; ++mi) at_[mi] = acs_s[wv * 64 + mi * 16 + fr];
  for (int k0 = 0; k0 < CHUNKC; k0 += 32) {
    if (k0 > wv * 64 + 63) break;   // all s > all t in this wave: fully masked
    float as_[8];
    *(float4*)&as_[0] = *(const float4*)&acs_s[k0 + kb * 8];
    *(float4*)&as_[4] = *(const float4*)&acs_s[k0 + kb * 8 + 4];
    bf16x8 b_[4];
#pragma unroll
    for (int ni = 0; ni < 4; ++ni)
      b_[ni] = *(const bf16x8*)&xt[(ni * 16 + fr) * 264 + k0 + kb * 8];
#pragma unroll
    for (int mi = 0; mi < 4; ++mi) {
      const int t = wv * 64 + mi * 16 + fr;
      uint4 cb4 = *(const uint4*)(cbbase + (size_t)t * CHUNKC + k0 + kb * 8);
      const unsigned cc[4] = {cb4.x, cb4.y, cb4.z, cb4.w};
      float p[8];
#pragma unroll
      for (int e = 0; e < 4; ++e) {
        const int sb = k0 + kb * 8 + 2 * e;
        const float c0 = bf2f((unsigned short)(cc[e] & 0xffff));
        const float c1 = bf2f((unsigned short)(cc[e] >> 16));
        p[2 * e] = (sb <= t) ? expf(at_[mi] - as_[2 * e]) * c0 : 0.f;
        p[2 * e + 1] = (sb + 1 <= t) ? expf(at_[mi] - as_[2 * e + 1]) * c1 : 0.f;
      }
      uint4 pu;
      pu.x = cvtpk(p[0], p[1]); pu.y = cvtpk(p[2], p[3]);
      pu.z = cvtpk(p[4], p[5]); pu.w = cvtpk(p[6], p[7]);
      bf16x8 af = *(const bf16x8*)&pu;
#pragma unroll
      for (int ni = 0; ni < 4; ++ni)
        acc[mi][ni] = __builtin_amdgcn_mfma_f32_16x16x32_bf16(af, b_[ni], acc[mi][ni], 0, 0, 0);
    }
  }

  // epilogue: Y[t][h*64+d] bf16
#pragma unroll
  for (int mi = 0; mi < 4; ++mi)
#pragma unroll
    for (int ni = 0; ni < 4; ++ni) {
      const int d = ni * 16 + fr;
#pragma unroll
      for (int r = 0; r < 4; ++r) {
        const int t = wv * 64 + mi * 16 + kb * 4 + r;
        Ybuf[(size_t)(b * SEQ + c * CHUNKC + t) * D_INNERC + h * DHEAD + d] = f2bf(acc[mi][ni][r]);
      }
    }
}

// ---------------- 10. out-norm * silu(gate), in place on Y bf16 ----------------
__global__ __launch_bounds__(256) void ynorm_kernel(
    unsigned short* __restrict__ Ybuf, const unsigned short* __restrict__ gate,
    const float* __restrict__ onw) {
  const int row = blockIdx.x;
  const int tid = threadIdx.x;
  unsigned short* yrow = Ybuf + (size_t)row * D_INNERC;
  const unsigned short* grow = gate + (size_t)row * D_INNERC;
  float v[16];
  float ss = 0.f;
#pragma unroll
  for (int i = 0; i < 2; ++i) {
    const int g8 = tid + i * 256;
    const uint4 q = ((const uint4*)yrow)[g8];
    const unsigned qq[4] = {q.x, q.y, q.z, q.w};
#pragma unroll
    for (int j = 0; j < 4; ++j) {
      const float a = bf2f((unsigned short)(qq[j] & 0xffff));
      const float bb = bf2f((unsigned short)(qq[j] >> 16));
      v[i * 8 + 2 * j] = a;
      v[i * 8 + 2 * j + 1] = bb;
      ss += a * a + bb * bb;
    }
  }
  ss = block_sum256(ss);
  const float rms = rsqrtf(ss * (1.0f / D_INNERC) + 1e-6f);
#pragma unroll
  for (int i = 0; i < 2; ++i) {
    const int g8 = tid + i * 256;
    const uint4 gq = ((const uint4*)grow)[g8];
    const unsigned gg[4] = {gq.x, gq.y, gq.z, gq.w};
    const float4 w0 = ((const float4*)onw)[g8 * 2];
    const float4 w1 = ((const float4*)onw)[g8 * 2 + 1];
    const float w_[8] = {w0.x, w0.y, w0.z, w0.w, w1.x, w1.y, w1.z, w1.w};
    uint4 o;
    unsigned oo[4];
#pragma unroll
    for (int j = 0; j < 4; ++j) {
      const float ga = siluf(bf2f((unsigned short)(gg[j] & 0xffff)));
      const float gb = siluf(bf2f((unsigned short)(gg[j] >> 16)));
      const float ya = v[i * 8 + 2 * j] * rms * w_[2 * j] * ga;
      const float yb = v[i * 8 + 2 * j + 1] * rms * w_[2 * j + 1] * gb;
      oo[j] = (unsigned)f2bf(ya) | ((unsigned)f2bf(yb) << 16);
    }
    o.x = oo[0]; o.y = oo[1]; o.z = oo[2]; o.w = oo[3];
    ((uint4*)yrow)[g8] = o;
  }
}

extern "C" void kernel_launch(void* const* d_in, const int* in_sizes, int n_in,
                              void* d_out, int out_size, void* d_ws, size_t ws_size,
                              hipStream_t stream) {
  const float* x           = (const float*)d_in[0];
  const float* norm_w      = (const float*)d_in[1];
  const float* in_proj_w   = (const float*)d_in[2];
  const float* conv_w      = (const float*)d_in[3];
  const float* conv_b      = (const float*)d_in[4];
  const float* conv_norm_w = (const float*)d_in[5];
  const float* A_log       = (const float*)d_in[6];
  const float* dt_w        = (const float*)d_in[7];
  const float* dt_b        = (const float*)d_in[8];
  const float* out_norm_w  = (const float*)d_in[9];
  const float* out_proj_w  = (const float*)d_in[10];
  float* out = (float*)d_out;
  char* base = (char*)d_ws;

  unsigned short* convin  = (unsigned short*)(base);
  unsigned short* Ybuf    = (unsigned short*)(base);                // alias (convin dead)
  unsigned short* convout = (unsigned short*)(base + 50331648ull);
  unsigned short* W1hi    = (unsigned short*)(base + 50331648ull);  // alias, pre-conv_norm
  unsigned short* W2hi    = (unsigned short*)(base + 50331648ull);  // alias, post-y
  unsigned short* gate    = (unsigned short*)(base + 100663296ull);
  unsigned short* xnhi    = (unsigned short*)(base + 134217728ull);
  unsigned short* CBbuf   = (unsigned short*)(base + 134217728ull); // alias (xn dead)
  unsigned short* xnlo    = (unsigned short*)(base + 150994944ull);
  float*          states  = (float*)(base + 167772160ull);
  float*          A_dt    = (float*)(base + 201326592ull);
  float*          Aarr    = (float*)(base + 202375168ull);
  float*          Acs     = (float*)(base + 203423744ull);

  if (ws_size < 204472320ull) return;  // fail-clean signature: Output0 err == 5.9375

  float* hfinal = out + 8388608ull;

  rmsnorm_in_kernel<<<ROWS, 256, 0, stream>>>(x, norm_w, xnhi, xnlo);
  wconv_kernel<<<(10368 * 2048 / 8 + 255) / 256, 256, 0, stream>>>(
      in_proj_w, W1hi, IN_PROJC * D_MODELC, 10368 * 2048);
  mfma_gemm_fast<0><<<dim3(ROWS / 128, 81), 256, 0, stream>>>(
      xnhi, D_MODELC, W1hi, D_MODELC, 32,
      convin, A_dt, gate, nullptr, nullptr, 0);
  mfma_gemm_split<<<dim3(ROWS / 128, 1), 256, 0, stream>>>(
      xnhi, xnlo, D_MODELC, in_proj_w, IN_PROJC, D_MODELC, 32,
      convin, A_dt, gate);
  conv_norm_kernel<<<ROWS, 256, 0, stream>>>(convin, conv_w, conv_b, conv_norm_w, convout);
  dt_kernel<<<ROWS, 64, 0, stream>>>(A_dt, dt_w, dt_b, A_log, Aarr);
  cumsum_kernel<<<BATCH * NCHUNK * NH, 256, 0, stream>>>(Aarr, Acs);
  cb_mfma_kernel<<<BATCH * NCHUNK * NG * 4, 256, 0, stream>>>(convout, CBbuf);
  states_kernel<<<BATCH * NCHUNK * NH, 256, 0, stream>>>(convout, Acs, states);
  chunkscan_kernel<<<4096, 256, 0, stream>>>(states, Acs, hfinal);
  y_mfma_kernel<<<BATCH * NCHUNK * NH, 256, 0, stream>>>(convout, Acs, CBbuf, states, Ybuf);
  wconv_kernel<<<(2048 * 4096 / 8 + 255) / 256, 256, 0, stream>>>(
      out_proj_w, W2hi, D_MODELC * D_INNERC, 2048 * 4096);
  ynorm_kernel<<<ROWS, 256, 0, stream>>>(Ybuf, gate, out_norm_w);
  mfma_gemm_fast<1><<<dim3(ROWS / 128, D_MODELC / 128), 256, 0, stream>>>(
      Ybuf, D_INNERC, W2hi, D_INNERC, -1,
      nullptr, nullptr, nullptr, out, x, D_MODELC);
}